// Round 12
// baseline (768.304 us; speedup 1.0000x reference)
//
#include <hip/hip_runtime.h>

#define L_LEN 39904
#define NT 624
#define RCH 120
#define SCH 240
#define CMEL 80
#define NQO 256
#define NBLK 16
#define KUP 800

typedef unsigned short u16;
typedef __attribute__((ext_vector_type(8))) short short8;
typedef __attribute__((ext_vector_type(4))) float f32x4;

#define MFMA(a, b, c) __builtin_amdgcn_mfma_f32_16x16x32_bf16((a), (b), (c), 0, 0, 0)

__device__ __forceinline__ u16 f2bf(float f) {
    unsigned u = __float_as_uint(f);
    u += 0x7FFFu + ((u >> 16) & 1u);
    return (u16)(u >> 16);
}
__device__ __forceinline__ unsigned pack2(float a, float b) {
    return (unsigned)f2bf(a) | ((unsigned)f2bf(b) << 16);
}
__device__ __forceinline__ float b16tof(u16 h) {
    return __uint_as_float((unsigned)h << 16);
}
// fast gating: tanh(a)*sigmoid(b) via v_exp + v_rcp (err ~1e-7, << bf16 noise)
__device__ __forceinline__ float gate(float a, float b) {
    float ea = __expf(2.f * a);
    float th = 1.f - 2.f * __builtin_amdgcn_rcpf(ea + 1.f);
    float sg = __builtin_amdgcn_rcpf(1.f + __expf(-b));
    return th * sg;
}

// ---- fallback ws layout ----
constexpr size_t O_CONDT = 0;
constexpr size_t O_RESA  = O_CONDT + 7023104;
constexpr size_t O_RESB  = O_RESA + 19153920;
constexpr size_t O_SKIP  = O_RESB + 19153920;
constexpr size_t O_ZFRAG = O_SKIP + 19153920;
constexpr size_t O_SKF   = O_ZFRAG + 2621440;
constexpr size_t O_RF    = O_SKF + 1048576;
constexpr size_t O_H1F   = O_RF + 524288;
constexpr size_t O_H2F   = O_H1F + 131072;
constexpr size_t O_UPF   = O_H2F + 131072;
constexpr size_t O_ZB    = O_UPF + 13107200;
constexpr size_t O_SKB   = O_ZB + 16384;

// ---- h-path layout (byte-identical to accepted r8/r10 runs) ----
constexpr size_t H2_CONDT = 0;                      // [L][88] bf16
constexpr size_t H2_RESF  = 7023104;                // unused slot
constexpr size_t H2_BFA   = H2_RESF + 19153920;     // [L][120] bf16
constexpr size_t H2_BFB   = H2_BFA + 9576960;       // [L][120] bf16
constexpr size_t H2_ZFRAG = H2_BFB + 9576960;
constexpr size_t H2_SKF   = H2_ZFRAG + 2621440;
constexpr size_t H2_RF    = H2_SKF + 1048576;
constexpr size_t H2_H1F   = H2_RF + 524288;
constexpr size_t H2_H2F   = H2_H1F + 131072;
constexpr size_t H2_ZB    = H2_H2F + 131072;
constexpr size_t H2_SKBS  = H2_ZB + 16384;
constexpr size_t H2_HALL  = H2_SKBS + 16384;        // h tensor / skip partials / upf overlay
constexpr size_t H_BYTES  = (size_t)NBLK * L_LEN * 120 * 2;
constexpr size_t UPF_BYTES = 13107200;
constexpr size_t NEED_H = H2_HALL + (H_BYTES > UPF_BYTES ? H_BYTES : UPF_BYTES);

// ================= prep kernels =================
__global__ void k_prep_zfrag(const float* __restrict__ bc_w, const float* __restrict__ bq_w,
                             u16* __restrict__ dst) {
    int i = blockIdx.x * 256 + threadIdx.x;
    if (i >= NBLK * 10 * 16 * 512) return;
    int jj = i & 7, lane = (i >> 3) & 63, mt = (i >> 9) & 15;
    int rest = i >> 13, ks = rest % 10, blk = rest / 10;
    int m = mt * 16 + (lane & 15);
    int k = ks * 32 + ((lane >> 4) << 3) + jj;
    float v = 0.f;
    if (m < 240) {
        int o = (m & 1) ? (m >> 1) + 120 : (m >> 1);
        if (k < 120)       v = bc_w[((size_t)(blk * 240 + o) * 120 + k) * 2 + 0];
        else if (k < 240)  v = bc_w[((size_t)(blk * 240 + o) * 120 + (k - 120)) * 2 + 1];
        else               v = bq_w[(size_t)(blk * 240 + o) * 80 + (k - 240)];
    }
    dst[i] = f2bf(v);
}
__global__ void k_prep_skfrag(const float* __restrict__ bs_w, u16* __restrict__ dst) {
    int i = blockIdx.x * 256 + threadIdx.x;
    if (i >= NBLK * 4 * 16 * 512) return;
    int jj = i & 7, lane = (i >> 3) & 63, mt = (i >> 9) & 15;
    int rest = i >> 13, ks = rest & 3, blk = rest >> 2;
    int m = mt * 16 + (lane & 15);
    int k = ks * 32 + ((lane >> 4) << 3) + jj;
    float v = (m < 240 && k < 120) ? bs_w[(size_t)(blk * 240 + m) * 120 + k] : 0.f;
    dst[i] = f2bf(v);
}
__global__ void k_prep_rfrag(const float* __restrict__ br_w, u16* __restrict__ dst) {
    int i = blockIdx.x * 256 + threadIdx.x;
    if (i >= NBLK * 4 * 8 * 512) return;
    int jj = i & 7, lane = (i >> 3) & 63, mt = (i >> 9) & 7;
    int rest = i >> 12, ks = rest & 3, blk = rest >> 2;
    int m = mt * 16 + (lane & 15);
    int k = ks * 32 + ((lane >> 4) << 3) + jj;
    float v = (m < 120 && k < 120) ? br_w[(size_t)(blk * 120 + m) * 120 + k] : 0.f;
    dst[i] = f2bf(v);
}
__global__ void k_prep_h1frag(const float* __restrict__ h1_w, u16* __restrict__ dst) {
    int i = blockIdx.x * 256 + threadIdx.x;
    if (i >= 8 * 16 * 512) return;
    int jj = i & 7, lane = (i >> 3) & 63, mt = (i >> 9) & 15, ks = i >> 13;
    int m = mt * 16 + (lane & 15);
    int k = ks * 32 + ((lane >> 4) << 3) + jj;
    float v = (k < 240) ? h1_w[(size_t)m * 240 + k] : 0.f;
    dst[i] = f2bf(v);
}
__global__ void k_prep_h2frag(const float* __restrict__ h2_w, u16* __restrict__ dst) {
    int i = blockIdx.x * 256 + threadIdx.x;
    if (i >= 8 * 16 * 512) return;
    int jj = i & 7, lane = (i >> 3) & 63, mt = (i >> 9) & 15, ks = i >> 13;
    int m = mt * 16 + (lane & 15);
    int k = ks * 32 + ((lane >> 4) << 3) + jj;
    dst[i] = f2bf(h2_w[(size_t)m * 256 + k]);
}
__global__ void k_prep_upfrag(const float* __restrict__ up_w, u16* __restrict__ dst) {
    int i = blockIdx.x * 256 + threadIdx.x;
    if (i >= 256 * 10 * 5 * 512) return;
    int jj = i & 7, lane = (i >> 3) & 63;
    int rest = i >> 9;
    int mt = rest % 5; rest /= 5;
    int ks = rest % 10; int p = rest / 10;
    int m = mt * 16 + (lane & 15);
    int k = ks * 32 + ((lane >> 4) << 3) + jj;
    int c = k >> 2, j = k & 3;
    int r = (256 - ((p + 1) & 255)) & 255;
    int kk = r + 256 * j;
    float v = (m < 80 && kk < KUP) ? up_w[((size_t)m * 80 + c) * KUP + kk] : 0.f;
    dst[i] = f2bf(v);
}
__global__ void k_prep_zbias(const float* __restrict__ bc_b, const float* __restrict__ bq_b,
                             float* __restrict__ dst) {
    int i = blockIdx.x * 256 + threadIdx.x;
    if (i >= NBLK * 256) return;
    int m = i & 255, blk = i >> 8;
    float v = 0.f;
    if (m < 240) {
        int o = (m & 1) ? (m >> 1) + 120 : (m >> 1);
        v = bc_b[blk * 240 + o] + bq_b[blk * 240 + o];
    }
    dst[i] = v;
}
__global__ void k_prep_skbias(const float* __restrict__ bs_b, float* __restrict__ dst) {
    int i = blockIdx.x * 256 + threadIdx.x;
    if (i >= NBLK * 240) return;
    dst[i] = bs_b[i];
}
__global__ void k_prep_skbsum(const float* __restrict__ bs_b, float* __restrict__ dst) {
    int m = blockIdx.x * 256 + threadIdx.x;
    if (m >= 240) return;
    float s = 0.f;
    for (int i = 0; i < NBLK; i++) s += bs_b[i * 240 + m];
    dst[m] = s;
}
__global__ void k_res_initT(const float* __restrict__ wav, const float* __restrict__ in_w,
                            const float* __restrict__ in_b, float* __restrict__ resT) {
    int i = blockIdx.x * 256 + threadIdx.x;
    if (i >= L_LEN * RCH) return;
    int t = i / RCH, c = i % RCH;
    resT[i] = wav[t] * in_w[c] + in_b[c];
}
// h-path: bf16 res carrier only
__global__ void k_res_initTb(const float* __restrict__ wav, const float* __restrict__ in_w,
                             const float* __restrict__ in_b, u16* __restrict__ resB) {
    int i = blockIdx.x * 256 + threadIdx.x;
    if (i >= L_LEN * RCH) return;
    int t = i / RCH, c = i % RCH;
    resB[i] = f2bf(wav[t] * in_w[c] + in_b[c]);
}

// ================= upsample (MFMA, per phase p) =================
__global__ __launch_bounds__(256) void k_up(const float* __restrict__ mel,
        const u16* __restrict__ upf, const float* __restrict__ up_b,
        u16* __restrict__ condT) {
    __shared__ u16 s_ms[64 * 328];
    const int tid = threadIdx.x, l = tid & 63, w = tid >> 6;
    const int quad = l >> 4, tloc = l & 15;
    const int p = blockIdx.x, s0 = blockIdx.y * 64;
    for (int rr = 0; rr < 16; rr++) {
        int tt = w + 4 * rr;
        int sg = s0 + tt;
        #pragma unroll
        for (int base = 0; base < 320; base += 64) {
            int ck = base + l;
            int c = ck >> 2, j = ck & 3;
            int mi = 1 + j + sg;
            float v = (mi < 160) ? mel[c * 160 + mi] : 0.f;
            s_ms[tt * 328 + ck] = f2bf(v);
        }
    }
    __syncthreads();
    f32x4 acc[2][4];
    #pragma unroll
    for (int i = 0; i < 2; i++)
        #pragma unroll
        for (int n = 0; n < 4; n++) acc[i][n] = (f32x4){0.f, 0.f, 0.f, 0.f};
    const int nmt = (w == 0) ? 2 : 1;
    int mts[2]; mts[0] = w; mts[1] = 4;
    for (int ks = 0; ks < 10; ks++) {
        short8 b[4];
        int k0 = ks * 32 + quad * 8;
        #pragma unroll
        for (int n = 0; n < 4; n++)
            b[n] = *(const short8*)&s_ms[(n * 16 + tloc) * 328 + k0];
        const short8* ap = (const short8*)(upf) + ((size_t)p * 10 + ks) * 5 * 64;
        for (int i = 0; i < nmt; i++) {
            short8 a = ap[mts[i] * 64 + l];
            #pragma unroll
            for (int n = 0; n < 4; n++) acc[i][n] = MFMA(a, b[n], acc[i][n]);
        }
    }
    for (int i = 0; i < nmt; i++) {
        int o_base = mts[i] * 16 + quad * 4;
        float4 ub = *(const float4*)(up_b + o_base);
        float bb[4] = {ub.x, ub.y, ub.z, ub.w};
        #pragma unroll
        for (int n = 0; n < 4; n++) {
            int sg = s0 + n * 16 + tloc;
            int t = p + 256 * sg;
            if (t < L_LEN) {
                #pragma unroll
                for (int r = 0; r < 4; r++)
                    condT[(size_t)t * 88 + o_base + r] = f2bf(acc[i][n][r] + bb[r]);
            }
        }
    }
}

// ================= WaveNet block — FALLBACK (proven path, unchanged) =================
__global__ __launch_bounds__(512, 4) void k_block(
        const u16* __restrict__ condT, const float* __restrict__ resT_in,
        float* __restrict__ resT_out, u16* __restrict__ skipT,
        const u16* __restrict__ zfrag, const u16* __restrict__ skfrag,
        const u16* __restrict__ rfrag, const float* __restrict__ zbias,
        const float* __restrict__ skbias, const float* __restrict__ resb,
        int blk, int dil, int first) {
    __shared__ u16 s_x[64 * 328];
    u16* s_h = s_x;
    const int tid = threadIdx.x, l = tid & 63, w = tid >> 6;
    const int quad = l >> 4, tloc = l & 15;
    const int t0 = blockIdx.x * 64;
    const short8* zap = (const short8*)(zfrag) + (size_t)blk * 10 * 16 * 64;
    short8 a_cur[2], a_nxt[2];
    #pragma unroll
    for (int i = 0; i < 2; i++) a_cur[i] = zap[(size_t)(w * 2 + i) * 64 + l];
    for (int rr = 0; rr < 8; rr++) {
        int tt = w + 8 * rr;
        int tg = t0 + tt, tp = tg - dil;
        if (l < 60) {
            float2 pv = make_float2(0.f, 0.f), cv = make_float2(0.f, 0.f);
            if (tp >= 0 && tp < L_LEN) pv = *(const float2*)(resT_in + (size_t)tp * 120 + 2 * l);
            if (tg < L_LEN)            cv = *(const float2*)(resT_in + (size_t)tg * 120 + 2 * l);
            *(unsigned*)&s_x[tt * 328 + 2 * l]       = pack2(pv.x, pv.y);
            *(unsigned*)&s_x[tt * 328 + 120 + 2 * l] = pack2(cv.x, cv.y);
        }
        if (l < 40) {
            unsigned q = 0;
            if (tg < L_LEN) q = *(const unsigned*)(condT + (size_t)tg * 88 + 2 * l);
            *(unsigned*)&s_x[tt * 328 + 240 + 2 * l] = q;
        }
    }
    __syncthreads();
    f32x4 acc[2][4];
    #pragma unroll
    for (int i = 0; i < 2; i++)
        #pragma unroll
        for (int n = 0; n < 4; n++) acc[i][n] = (f32x4){0.f, 0.f, 0.f, 0.f};
    for (int ks = 0; ks < 10; ks++) {
        if (ks < 9) {
            #pragma unroll
            for (int i = 0; i < 2; i++)
                a_nxt[i] = zap[((size_t)(ks + 1) * 16 + w * 2 + i) * 64 + l];
        }
        int k0 = ks * 32 + quad * 8;
        short8 b[4];
        #pragma unroll
        for (int n = 0; n < 4; n++)
            b[n] = *(const short8*)&s_x[(n * 16 + tloc) * 328 + k0];
        #pragma unroll
        for (int i = 0; i < 2; i++)
            #pragma unroll
            for (int n = 0; n < 4; n++) acc[i][n] = MFMA(a_cur[i], b[n], acc[i][n]);
        #pragma unroll
        for (int i = 0; i < 2; i++) a_cur[i] = a_nxt[i];
    }
    const short8* sap = (const short8*)(skfrag) + (size_t)blk * 4 * 16 * 64;
    const short8* rap = (const short8*)(rfrag) + (size_t)blk * 4 * 8 * 64;
    short8 sa_c[2], sa_n[2], ra_c, ra_n;
    #pragma unroll
    for (int i = 0; i < 2; i++) sa_c[i] = sap[(size_t)(w * 2 + i) * 64 + l];
    ra_c = rap[(size_t)w * 64 + l];
    uint2 skp[2][4];
    if (!first) {
        #pragma unroll
        for (int i = 0; i < 2; i++) {
            int m_base = (w * 2 + i) * 16 + quad * 4;
            if (m_base < 240) {
                #pragma unroll
                for (int n = 0; n < 4; n++) {
                    int t = t0 + n * 16 + tloc;
                    if (t < L_LEN)
                        skp[i][n] = *(const uint2*)(skipT + (size_t)t * 240 + m_base);
                }
            }
        }
    }
    unsigned hu[2][4];
    #pragma unroll
    for (int i = 0; i < 2; i++) {
        int m_base = (w * 2 + i) * 16 + quad * 4;
        float4 bz4 = *(const float4*)(zbias + blk * 256 + m_base);
        #pragma unroll
        for (int n = 0; n < 4; n++) {
            float h0 = gate(acc[i][n][0] + bz4.x, acc[i][n][1] + bz4.y);
            float h1 = gate(acc[i][n][2] + bz4.z, acc[i][n][3] + bz4.w);
            hu[i][n] = pack2(h0, h1);
        }
    }
    __syncthreads();
    #pragma unroll
    for (int i = 0; i < 2; i++) {
        int j0 = (w * 2 + i) * 8 + quad * 2;
        #pragma unroll
        for (int n = 0; n < 4; n++)
            *(unsigned*)&s_h[(n * 16 + tloc) * 136 + j0] = hu[i][n];
    }
    __syncthreads();
    f32x4 sacc[2][4], racc[4];
    #pragma unroll
    for (int i = 0; i < 2; i++)
        #pragma unroll
        for (int n = 0; n < 4; n++) sacc[i][n] = (f32x4){0.f, 0.f, 0.f, 0.f};
    #pragma unroll
    for (int n = 0; n < 4; n++) racc[n] = (f32x4){0.f, 0.f, 0.f, 0.f};
    for (int ks = 0; ks < 4; ks++) {
        if (ks < 3) {
            #pragma unroll
            for (int i = 0; i < 2; i++)
                sa_n[i] = sap[((size_t)(ks + 1) * 16 + w * 2 + i) * 64 + l];
            ra_n = rap[((size_t)(ks + 1) * 8 + w) * 64 + l];
        }
        short8 b[4];
        int k0 = ks * 32 + quad * 8;
        #pragma unroll
        for (int n = 0; n < 4; n++)
            b[n] = *(const short8*)&s_h[(n * 16 + tloc) * 136 + k0];
        #pragma unroll
        for (int i = 0; i < 2; i++)
            #pragma unroll
            for (int n = 0; n < 4; n++) sacc[i][n] = MFMA(sa_c[i], b[n], sacc[i][n]);
        #pragma unroll
        for (int n = 0; n < 4; n++) racc[n] = MFMA(ra_c, b[n], racc[n]);
        #pragma unroll
        for (int i = 0; i < 2; i++) sa_c[i] = sa_n[i];
        ra_c = ra_n;
    }
    #pragma unroll
    for (int i = 0; i < 2; i++) {
        int m_base = (w * 2 + i) * 16 + quad * 4;
        if (m_base >= 240) continue;
        float4 sb4 = *(const float4*)(skbias + blk * 240 + m_base);
        #pragma unroll
        for (int n = 0; n < 4; n++) {
            int t = t0 + n * 16 + tloc;
            if (t >= L_LEN) continue;
            float x0 = sacc[i][n][0] + sb4.x;
            float x1 = sacc[i][n][1] + sb4.y;
            float x2 = sacc[i][n][2] + sb4.z;
            float x3 = sacc[i][n][3] + sb4.w;
            if (!first) {
                uint2 pv = skp[i][n];
                x0 += b16tof((u16)(pv.x & 0xFFFF));
                x1 += b16tof((u16)(pv.x >> 16));
                x2 += b16tof((u16)(pv.y & 0xFFFF));
                x3 += b16tof((u16)(pv.y >> 16));
            }
            uint2 ov;
            ov.x = pack2(x0, x1);
            ov.y = pack2(x2, x3);
            *(uint2*)(skipT + (size_t)t * 240 + m_base) = ov;
        }
    }
    {
        int m_base = w * 16 + quad * 4;
        if (m_base < 120) {
            float4 rb4 = *(const float4*)(resb + blk * 120 + m_base);
            #pragma unroll
            for (int n = 0; n < 4; n++) {
                int t = t0 + n * 16 + tloc;
                if (t >= L_LEN) continue;
                float4 cur = *(const float4*)(resT_in + (size_t)t * 120 + m_base);
                float4 o;
                o.x = cur.x + racc[n][0] + rb4.x;
                o.y = cur.y + racc[n][1] + rb4.y;
                o.z = cur.z + racc[n][2] + rb4.z;
                o.w = cur.w + racc[n][3] + rb4.w;
                *(float4*)(resT_out + (size_t)t * 120 + m_base) = o;
            }
        }
    }
}

// ===== single-layer WaveNet block (r5/r8 proven, dil>=16): bf16 carrier, LDS past-copy =====
__global__ __launch_bounds__(512, 4) void k_block_h4(
        const u16* __restrict__ condT,
        const u16* __restrict__ bfIn, u16* __restrict__ bfOut,
        u16* __restrict__ hout,
        const u16* __restrict__ zfrag, const u16* __restrict__ rfrag,
        const float* __restrict__ zbias, const float* __restrict__ resb,
        int blk, int dil) {
    __shared__ u16 s_x[64 * 328];
    u16* s_h = s_x;
    const int tid = threadIdx.x, l = tid & 63, w = tid >> 6;
    const int quad = l >> 4, tloc = l & 15;
    const int t0 = blockIdx.x * 64;
    const short8* zap = (const short8*)(zfrag) + (size_t)blk * 10 * 16 * 64;
    short8 a_cur[2], a_nxt[2];
    a_cur[0] = zap[(size_t)(w * 2 + 0) * 64 + l];
    a_cur[1] = zap[(size_t)(w * 2 + 1) * 64 + l];
    const uint2 Z2 = make_uint2(0u, 0u);
    for (int rr = 0; rr < 8; rr++) {
        int tt = w + 8 * rr, tg = t0 + tt;
        if (l < 30) {
            uint2 cv = (tg < L_LEN) ? *(const uint2*)(bfIn + (size_t)tg * 120 + 4 * l) : Z2;
            *(uint2*)&s_x[tt * 328 + 120 + 4 * l] = cv;
            if (tt < dil) {
                int tp = tg - dil;
                uint2 pv = (tp >= 0 && tp < L_LEN)
                    ? *(const uint2*)(bfIn + (size_t)tp * 120 + 4 * l) : Z2;
                *(uint2*)&s_x[tt * 328 + 4 * l] = pv;
            }
        } else if (l >= 32 && l < 54) {
            int c = l - 32;
            uint2 q = (tg < L_LEN) ? *(const uint2*)(condT + (size_t)tg * 88 + 4 * c) : Z2;
            *(uint2*)&s_x[tt * 328 + 240 + 4 * c] = q;
        }
    }
    __syncthreads();
    if (dil < 64) {
        for (int rr = 0; rr < 8; rr++) {
            int tt = w + 8 * rr;
            if (l < 30 && tt >= dil)
                *(uint2*)&s_x[tt * 328 + 4 * l] =
                    *(const uint2*)&s_x[(tt - dil) * 328 + 120 + 4 * l];
        }
        __syncthreads();
    }
    f32x4 acc[2][4];
    #pragma unroll
    for (int i = 0; i < 2; i++)
        #pragma unroll
        for (int n = 0; n < 4; n++) acc[i][n] = (f32x4){0.f, 0.f, 0.f, 0.f};
    for (int ks = 0; ks < 10; ks++) {
        if (ks < 9) {
            a_nxt[0] = zap[((size_t)(ks + 1) * 16 + w * 2 + 0) * 64 + l];
            a_nxt[1] = zap[((size_t)(ks + 1) * 16 + w * 2 + 1) * 64 + l];
        }
        int k0 = ks * 32 + quad * 8;
        short8 b[4];
        #pragma unroll
        for (int n = 0; n < 4; n++)
            b[n] = *(const short8*)&s_x[(n * 16 + tloc) * 328 + k0];
        #pragma unroll
        for (int i = 0; i < 2; i++)
            #pragma unroll
            for (int n = 0; n < 4; n++) acc[i][n] = MFMA(a_cur[i], b[n], acc[i][n]);
        a_cur[0] = a_nxt[0]; a_cur[1] = a_nxt[1];
    }
    const short8* rap = (const short8*)(rfrag) + (size_t)blk * 4 * 8 * 64;
    short8 ra_c = rap[(size_t)w * 64 + l], ra_n;
    const int m_r = w * 16 + quad * 4;
    uint2 curb[4];
    if (m_r < 120) {
        #pragma unroll
        for (int n = 0; n < 4; n++)
            curb[n] = *(const uint2*)&s_x[(n * 16 + tloc) * 328 + 120 + m_r];
    }
    unsigned hu[2][4];
    #pragma unroll
    for (int i = 0; i < 2; i++) {
        int m_base = (w * 2 + i) * 16 + quad * 4;
        float4 bz4 = *(const float4*)(zbias + blk * 256 + m_base);
        #pragma unroll
        for (int n = 0; n < 4; n++) {
            float h0 = gate(acc[i][n][0] + bz4.x, acc[i][n][1] + bz4.y);
            float h1 = gate(acc[i][n][2] + bz4.z, acc[i][n][3] + bz4.w);
            hu[i][n] = pack2(h0, h1);
        }
    }
    __syncthreads();
    #pragma unroll
    for (int i = 0; i < 2; i++) {
        int j0 = (w * 2 + i) * 8 + quad * 2;
        #pragma unroll
        for (int n = 0; n < 4; n++)
            *(unsigned*)&s_h[(n * 16 + tloc) * 136 + j0] = hu[i][n];
    }
    __syncthreads();
    for (int rr = 0; rr < 8; rr++) {
        int tt = w + 8 * rr, tg = t0 + tt;
        if (l < 60 && tg < L_LEN)
            *(unsigned*)&hout[(size_t)tg * 120 + 2 * l] =
                *(const unsigned*)&s_h[tt * 136 + 2 * l];
    }
    f32x4 racc[4];
    #pragma unroll
    for (int n = 0; n < 4; n++) racc[n] = (f32x4){0.f, 0.f, 0.f, 0.f};
    for (int ks = 0; ks < 4; ks++) {
        if (ks < 3) ra_n = rap[((size_t)(ks + 1) * 8 + w) * 64 + l];
        short8 b[4];
        int k0 = ks * 32 + quad * 8;
        #pragma unroll
        for (int n = 0; n < 4; n++)
            b[n] = *(const short8*)&s_h[(n * 16 + tloc) * 136 + k0];
        #pragma unroll
        for (int n = 0; n < 4; n++) racc[n] = MFMA(ra_c, b[n], racc[n]);
        ra_c = ra_n;
    }
    if (m_r < 120) {
        float4 rb4 = *(const float4*)(resb + blk * 120 + m_r);
        #pragma unroll
        for (int n = 0; n < 4; n++) {
            int t = t0 + n * 16 + tloc;
            if (t >= L_LEN) continue;
            float o0 = b16tof((u16)(curb[n].x & 0xFFFF)) + racc[n][0] + rb4.x;
            float o1 = b16tof((u16)(curb[n].x >> 16))    + racc[n][1] + rb4.y;
            float o2 = b16tof((u16)(curb[n].y & 0xFFFF)) + racc[n][2] + rb4.z;
            float o3 = b16tof((u16)(curb[n].y >> 16))    + racc[n][3] + rb4.w;
            uint2 hv;
            hv.x = pack2(o0, o1);
            hv.y = pack2(o2, o3);
            *(uint2*)(bfOut + (size_t)t * 120 + m_r) = hv;
        }
    }
}

// ===== 4-layer group (dils 1,2,4,8) + in-group skip accumulation.
//       r11 fix: skip partial written via LDS transpose -> row-coalesced 480B stores. =====
__global__ __launch_bounds__(512, 4) void k_block_g4(
        const u16* __restrict__ condT,
        const u16* __restrict__ bfIn, u16* __restrict__ bfOut,
        u16* __restrict__ skpart,
        const u16* __restrict__ zfrag, const u16* __restrict__ skfrag,
        const u16* __restrict__ rfrag,
        const float* __restrict__ zbias, const float* __restrict__ resb,
        int base) {
    __shared__ u16 s_all[80 * 120 + 80 * 88 + 80 * 136];   // 55360 B
    u16* s_res  = s_all;                  // [80][120]
    u16* s_cond = s_all + 80 * 120;       // [80][88]
    u16* s_h    = s_all + 80 * 208;       // [80][136]
    const int tid = threadIdx.x, l = tid & 63, w = tid >> 6;
    const int quad = l >> 4, tloc = l & 15;
    const int t0 = blockIdx.x * 64;
    const uint2 Z2 = make_uint2(0u, 0u);
    // ---- stage 80 rows [t0-16, t0+64) of res (bf16) + cond ----
    for (int rr = 0; rr < 10; rr++) {
        int row = w + 8 * rr;
        int tg = t0 - 16 + row;
        bool ok = (tg >= 0 && tg < L_LEN);
        if (l < 30) {
            uint2 v = ok ? *(const uint2*)(bfIn + (size_t)tg * 120 + 4 * l) : Z2;
            *(uint2*)&s_res[row * 120 + 4 * l] = v;
        } else if (l >= 32 && l < 54) {
            int c = l - 32;
            uint2 q = ok ? *(const uint2*)(condT + (size_t)tg * 88 + 4 * c) : Z2;
            *(uint2*)&s_cond[row * 88 + 4 * c] = q;
        }
    }
    __syncthreads();
    const int m_r = w * 16 + quad * 4;
    // persistent skip accumulator across the 4 layers (cols = owned rows 16..79)
    f32x4 skacc[2][4];
    #pragma unroll
    for (int i = 0; i < 2; i++)
        #pragma unroll
        for (int n = 0; n < 4; n++) skacc[i][n] = (f32x4){0.f, 0.f, 0.f, 0.f};
    for (int k = 0; k < 4; k++) {
        const int blk = base + k;
        const int d = 1 << k;                    // 1,2,4,8
        const short8* zap = (const short8*)(zfrag) + (size_t)blk * 10 * 16 * 64;
        const short8* rap = (const short8*)(rfrag) + (size_t)blk * 4 * 8 * 64;
        const short8* sap = (const short8*)(skfrag) + (size_t)blk * 4 * 16 * 64;
        short8 a_cur[2], a_nxt[2];
        a_cur[0] = zap[(size_t)(w * 2 + 0) * 64 + l];
        a_cur[1] = zap[(size_t)(w * 2 + 1) * 64 + l];
        // ---- z GEMM: M=256 (2 mt/wave), K=320, N=80 (5 col-frags) ----
        f32x4 acc[2][5];
        #pragma unroll
        for (int i = 0; i < 2; i++)
            #pragma unroll
            for (int n = 0; n < 5; n++) acc[i][n] = (f32x4){0.f, 0.f, 0.f, 0.f};
        for (int ks = 0; ks < 10; ks++) {
            if (ks < 9) {
                a_nxt[0] = zap[((size_t)(ks + 1) * 16 + w * 2 + 0) * 64 + l];
                a_nxt[1] = zap[((size_t)(ks + 1) * 16 + w * 2 + 1) * 64 + l];
            }
            int k0 = ks * 32 + quad * 8;
            short8 b[5];
            #pragma unroll
            for (int n = 0; n < 5; n++) {
                int r = n * 16 + tloc;
                const u16* src;
                if (k0 < 120) {
                    int pr = r - d; if (pr < 0) pr = 0;   // clamped rows are invalid anyway
                    src = &s_res[pr * 120 + k0];
                } else if (k0 < 240) {
                    src = &s_res[r * 120 + (k0 - 120)];
                } else {
                    src = &s_cond[r * 88 + (k0 - 240)];
                }
                b[n] = *(const short8*)src;
            }
            #pragma unroll
            for (int i = 0; i < 2; i++)
                #pragma unroll
                for (int n = 0; n < 5; n++) acc[i][n] = MFMA(a_cur[i], b[n], acc[i][n]);
            a_cur[0] = a_nxt[0]; a_cur[1] = a_nxt[1];
        }
        // ---- gating ----
        unsigned hu[2][5];
        #pragma unroll
        for (int i = 0; i < 2; i++) {
            int m_base = (w * 2 + i) * 16 + quad * 4;
            float4 bz4 = *(const float4*)(zbias + blk * 256 + m_base);
            #pragma unroll
            for (int n = 0; n < 5; n++) {
                float h0 = gate(acc[i][n][0] + bz4.x, acc[i][n][1] + bz4.y);
                float h1 = gate(acc[i][n][2] + bz4.z, acc[i][n][3] + bz4.w);
                hu[i][n] = pack2(h0, h1);
            }
        }
        // ---- h transpose into s_h ----
        #pragma unroll
        for (int i = 0; i < 2; i++) {
            int j0 = (w * 2 + i) * 8 + quad * 2;
            #pragma unroll
            for (int n = 0; n < 5; n++)
                *(unsigned*)&s_h[(n * 16 + tloc) * 136 + j0] = hu[i][n];
        }
        __syncthreads();   // s_h ready; all z reads of s_res complete
        // ---- combined skip GEMM (2 mt, cols rows16..79) + res GEMM (1 mt, all 80 rows) ----
        f32x4 racc[5];
        #pragma unroll
        for (int n = 0; n < 5; n++) racc[n] = (f32x4){0.f, 0.f, 0.f, 0.f};
        short8 ra_c = rap[(size_t)w * 64 + l], ra_n;
        short8 sa_c[2], sa_n[2];
        sa_c[0] = sap[(size_t)(w * 2 + 0) * 64 + l];
        sa_c[1] = sap[(size_t)(w * 2 + 1) * 64 + l];
        for (int ks = 0; ks < 4; ks++) {
            if (ks < 3) {
                ra_n = rap[((size_t)(ks + 1) * 8 + w) * 64 + l];
                sa_n[0] = sap[((size_t)(ks + 1) * 16 + w * 2 + 0) * 64 + l];
                sa_n[1] = sap[((size_t)(ks + 1) * 16 + w * 2 + 1) * 64 + l];
            }
            short8 b[5];
            int k0 = ks * 32 + quad * 8;
            #pragma unroll
            for (int n = 0; n < 5; n++)
                b[n] = *(const short8*)&s_h[(n * 16 + tloc) * 136 + k0];
            #pragma unroll
            for (int n = 0; n < 5; n++) racc[n] = MFMA(ra_c, b[n], racc[n]);
            #pragma unroll
            for (int i = 0; i < 2; i++)
                #pragma unroll
                for (int n = 0; n < 4; n++)
                    skacc[i][n] = MFMA(sa_c[i], b[n + 1], skacc[i][n]);
            ra_c = ra_n;
            sa_c[0] = sa_n[0]; sa_c[1] = sa_n[1];
        }
        // ---- in-place res update (skip tglob<0: keep zero-padding; one owner/element) ----
        if (m_r < 120) {
            float4 rb4 = *(const float4*)(resb + blk * 120 + m_r);
            #pragma unroll
            for (int n = 0; n < 5; n++) {
                int row = n * 16 + tloc;
                int tg = t0 - 16 + row;
                if (tg < 0 || tg >= L_LEN) continue;
                uint2 cv = *(const uint2*)&s_res[row * 120 + m_r];
                float o0 = b16tof((u16)(cv.x & 0xFFFF)) + racc[n][0] + rb4.x;
                float o1 = b16tof((u16)(cv.x >> 16))    + racc[n][1] + rb4.y;
                float o2 = b16tof((u16)(cv.y & 0xFFFF)) + racc[n][2] + rb4.z;
                float o3 = b16tof((u16)(cv.y >> 16))    + racc[n][3] + rb4.w;
                uint2 hv;
                hv.x = pack2(o0, o1);
                hv.y = pack2(o2, o3);
                *(uint2*)&s_res[row * 120 + m_r] = hv;
            }
        }
        __syncthreads();   // s_res updated + s_h reads done before next layer
    }
    // ---- write final res (layer base+3 output) rows 16..79 to bfOut ----
    for (int rr = 0; rr < 8; rr++) {
        int row = 16 + w + 8 * rr;
        int tg = t0 + w + 8 * rr;
        if (l < 30 && tg < L_LEN)
            *(uint2*)(bfOut + (size_t)tg * 120 + 4 * l) =
                *(const uint2*)&s_res[row * 120 + 4 * l];
    }
    __syncthreads();   // all s_res reads done -> reuse LDS as transpose buffer
    // ---- transpose skacc into LDS, then row-coalesced [t][240] write ----
    u16* s_tr = s_all;   // [64][248] = 15872 u16, fits in s_all
    #pragma unroll
    for (int i = 0; i < 2; i++) {
        int m_base = (w * 2 + i) * 16 + quad * 4;
        if (m_base >= 240) continue;
        #pragma unroll
        for (int n = 0; n < 4; n++) {
            int tt = n * 16 + tloc;
            uint2 ov;
            ov.x = pack2(skacc[i][n][0], skacc[i][n][1]);
            ov.y = pack2(skacc[i][n][2], skacc[i][n][3]);
            *(uint2*)&s_tr[tt * 248 + m_base] = ov;
        }
    }
    __syncthreads();
    for (int rr = 0; rr < 8; rr++) {
        int tt = w + 8 * rr;
        int tg = t0 + tt;
        if (l < 60 && tg < L_LEN)
            *(uint2*)(skpart + (size_t)tg * 240 + 4 * l) =
                *(const uint2*)&s_tr[tt * 248 + 4 * l];
    }
}

// ================= head — FALLBACK (proven, restored) =================
__global__ __launch_bounds__(512, 4) void k_final(const u16* __restrict__ skipT,
        const u16* __restrict__ h1f, const u16* __restrict__ h2f,
        const float* __restrict__ h1_b, const float* __restrict__ h2_b,
        float* __restrict__ out) {
    __shared__ u16 s_m[64 * 264];
    const int tid = threadIdx.x, l = tid & 63, w = tid >> 6;
    const int quad = l >> 4, tloc = l & 15;
    const int t0 = blockIdx.x * 64;
    const short8* ap1 = (const short8*)h1f;
    short8 a_cur[2], a_nxt[2];
    #pragma unroll
    for (int i = 0; i < 2; i++) a_cur[i] = ap1[(size_t)(w * 2 + i) * 64 + l];
    for (int rr = 0; rr < 8; rr++) {
        int tt = w + 8 * rr;
        int tg = t0 + tt;
        uint2 v = make_uint2(0u, 0u);
        if (l < 60 && tg < L_LEN)
            v = *(const uint2*)(skipT + (size_t)tg * 240 + 4 * l);
        float x0 = fmaxf(b16tof((u16)(v.x & 0xFFFF)), 0.f);
        float x1 = fmaxf(b16tof((u16)(v.x >> 16)), 0.f);
        float x2 = fmaxf(b16tof((u16)(v.y & 0xFFFF)), 0.f);
        float x3 = fmaxf(b16tof((u16)(v.y >> 16)), 0.f);
        uint2 ov;
        ov.x = pack2(x0, x1);
        ov.y = pack2(x2, x3);
        *(uint2*)&s_m[tt * 264 + 4 * l] = ov;
    }
    __syncthreads();
    f32x4 acc[2][4];
    #pragma unroll
    for (int i = 0; i < 2; i++)
        #pragma unroll
        for (int n = 0; n < 4; n++) acc[i][n] = (f32x4){0.f, 0.f, 0.f, 0.f};
    for (int ks = 0; ks < 8; ks++) {
        if (ks < 7) {
            #pragma unroll
            for (int i = 0; i < 2; i++)
                a_nxt[i] = ap1[((size_t)(ks + 1) * 16 + w * 2 + i) * 64 + l];
        }
        short8 b[4];
        int k0 = ks * 32 + quad * 8;
        #pragma unroll
        for (int n = 0; n < 4; n++)
            b[n] = *(const short8*)&s_m[(n * 16 + tloc) * 264 + k0];
        #pragma unroll
        for (int i = 0; i < 2; i++)
            #pragma unroll
            for (int n = 0; n < 4; n++) acc[i][n] = MFMA(a_cur[i], b[n], acc[i][n]);
        #pragma unroll
        for (int i = 0; i < 2; i++) a_cur[i] = a_nxt[i];
    }
    unsigned ylo[2][4], yhi[2][4];
    #pragma unroll
    for (int i = 0; i < 2; i++) {
        int m_base = (w * 2 + i) * 16 + quad * 4;
        float4 b1 = *(const float4*)(h1_b + m_base);
        #pragma unroll
        for (int n = 0; n < 4; n++) {
            float y0 = fmaxf(acc[i][n][0] + b1.x, 0.f);
            float y1v = fmaxf(acc[i][n][1] + b1.y, 0.f);
            float y2 = fmaxf(acc[i][n][2] + b1.z, 0.f);
            float y3 = fmaxf(acc[i][n][3] + b1.w, 0.f);
            ylo[i][n] = pack2(y0, y1v);
            yhi[i][n] = pack2(y2, y3);
        }
    }
    const short8* ap2 = (const short8*)h2f;
    #pragma unroll
    for (int i = 0; i < 2; i++) a_cur[i] = ap2[(size_t)(w * 2 + i) * 64 + l];
    __syncthreads();
    #pragma unroll
    for (int i = 0; i < 2; i++) {
        int m_base = (w * 2 + i) * 16 + quad * 4;
        #pragma unroll
        for (int n = 0; n < 4; n++) {
            int t = n * 16 + tloc;
            *(unsigned*)&s_m[t * 264 + m_base]     = ylo[i][n];
            *(unsigned*)&s_m[t * 264 + m_base + 2] = yhi[i][n];
        }
    }
    __syncthreads();
    #pragma unroll
    for (int i = 0; i < 2; i++)
        #pragma unroll
        for (int n = 0; n < 4; n++) acc[i][n] = (f32x4){0.f, 0.f, 0.f, 0.f};
    for (int ks = 0; ks < 8; ks++) {
        if (ks < 7) {
            #pragma unroll
            for (int i = 0; i < 2; i++)
                a_nxt[i] = ap2[((size_t)(ks + 1) * 16 + w * 2 + i) * 64 + l];
        }
        short8 b[4];
        int k0 = ks * 32 + quad * 8;
        #pragma unroll
        for (int n = 0; n < 4; n++)
            b[n] = *(const short8*)&s_m[(n * 16 + tloc) * 264 + k0];
        #pragma unroll
        for (int i = 0; i < 2; i++)
            #pragma unroll
            for (int n = 0; n < 4; n++) acc[i][n] = MFMA(a_cur[i], b[n], acc[i][n]);
        #pragma unroll
        for (int i = 0; i < 2; i++) a_cur[i] = a_nxt[i];
    }
    #pragma unroll
    for (int i = 0; i < 2; i++) {
        int m_base = (w * 2 + i) * 16 + quad * 4;
        float4 b2 = *(const float4*)(h2_b + m_base);
        float bb[4] = {b2.x, b2.y, b2.z, b2.w};
        #pragma unroll
        for (int n = 0; n < 4; n++) {
            int t = t0 + n * 16 + tloc;
            if (t >= L_LEN) continue;
            #pragma unroll
            for (int r = 0; r < 4; r++)
                out[(size_t)(m_base + r) * L_LEN + t] = acc[i][n][r] + bb[r];
        }
    }
}

// ===== head v5: 8 single-layer h GEMM steps (double-buffered) + LDS-staged partial adds =====
__global__ __launch_bounds__(512, 4) void k_final_h5(const u16* __restrict__ hall,
        const u16* __restrict__ p0, const u16* __restrict__ p1,
        const u16* __restrict__ skf, const u16* __restrict__ h1f,
        const u16* __restrict__ h2f, const float* __restrict__ skbsum,
        const float* __restrict__ h1_b, const float* __restrict__ h2_b,
        float* __restrict__ out) {
    __shared__ u16 smem[2 * 64 * 136];
    u16* s_m = smem;
    const int tid = threadIdx.x, l = tid & 63, w = tid >> 6;
    const int quad = l >> 4, tloc = l & 15;
    const int t0 = blockIdx.x * 64;
    const short8* sap = (const short8*)skf;
    const int LL[8] = {4, 5, 6, 7, 12, 13, 14, 15};

    unsigned ha[8], hb[8];
    auto LOADH = [&](unsigned (&reg)[8], int layer) {
        const u16* hp = hall + (size_t)layer * ((size_t)L_LEN * 120);
        #pragma unroll
        for (int rr = 0; rr < 8; rr++) {
            int tg = t0 + w + 8 * rr;
            reg[rr] = (l < 60 && tg < L_LEN)
                ? *(const unsigned*)&hp[(size_t)tg * 120 + 2 * l] : 0u;
        }
    };
    // zero pad cols 120..127 of BOTH buffers once
    if (l >= 60) {
        #pragma unroll
        for (int rr = 0; rr < 8; rr++) {
            int row = w + 8 * rr;
            *(unsigned*)&smem[row * 136 + 2 * l] = 0u;
            *(unsigned*)&smem[64 * 136 + row * 136 + 2 * l] = 0u;
        }
    }
    LOADH(ha, LL[0]);
    #pragma unroll
    for (int rr = 0; rr < 8; rr++)
        if (l < 60) *(unsigned*)&smem[(w + 8 * rr) * 136 + 2 * l] = ha[rr];
    LOADH(hb, LL[1]);
    short8 sa_c[2], sa_n[2];
    sa_c[0] = sap[((size_t)(LL[0] * 4) * 16 + w * 2 + 0) * 64 + l];
    sa_c[1] = sap[((size_t)(LL[0] * 4) * 16 + w * 2 + 1) * 64 + l];
    f32x4 sacc[2][4];
    #pragma unroll
    for (int i = 0; i < 2; i++)
        #pragma unroll
        for (int n = 0; n < 4; n++) sacc[i][n] = (f32x4){0.f, 0.f, 0.f, 0.f};
    __syncthreads();
    // 8 steps, ONE barrier each: GEMM h_{LL[i]} while writing h_{LL[i+1]} and loading h_{LL[i+2]}
    #pragma unroll
    for (int i = 0; i < 8; i++) {
        u16* cur = smem + (i & 1) * (64 * 136);
        u16* nxt = smem + ((i + 1) & 1) * (64 * 136);
        unsigned (&wrg)[8] = (i & 1) ? ha : hb;
        unsigned (&lrg)[8] = (i & 1) ? hb : ha;
        if (i < 7) {
            #pragma unroll
            for (int rr = 0; rr < 8; rr++)
                if (l < 60) *(unsigned*)&nxt[(w + 8 * rr) * 136 + 2 * l] = wrg[rr];
        }
        if (i < 6) LOADH(lrg, LL[i + 2]);
        for (int ks = 0; ks < 4; ks++) {
            int idx = i * 4 + ks + 1;
            if (idx < 32) {
                int gn = LL[idx >> 2] * 4 + (idx & 3);
                sa_n[0] = sap[((size_t)gn * 16 + w * 2 + 0) * 64 + l];
                sa_n[1] = sap[((size_t)gn * 16 + w * 2 + 1) * 64 + l];
            }
            int k0 = ks * 32 + quad * 8;
            short8 b[4];
            #pragma unroll
            for (int n = 0; n < 4; n++)
                b[n] = *(const short8*)&cur[(n * 16 + tloc) * 136 + k0];
            #pragma unroll
            for (int i2 = 0; i2 < 2; i2++)
                #pragma unroll
                for (int n = 0; n < 4; n++)
                    sacc[i2][n] = MFMA(sa_c[i2], b[n], sacc[i2][n]);
            sa_c[0] = sa_n[0]; sa_c[1] = sa_n[1];
        }
        __syncthreads();
    }
    // ---- stage p0+p1 row-coalesced into LDS [64][248] (bf16 sum) ----
    u16* s_p = smem;
    for (int rr = 0; rr < 8; rr++) {
        int tt = w + 8 * rr;
        int tg = t0 + tt;
        if (l < 60) {
            uint2 bsum = make_uint2(0u, 0u);
            if (tg < L_LEN) {
                uint2 pa = *(const uint2*)(p0 + (size_t)tg * 240 + 4 * l);
                uint2 pb = *(const uint2*)(p1 + (size_t)tg * 240 + 4 * l);
                float v0 = b16tof((u16)(pa.x & 0xFFFF)) + b16tof((u16)(pb.x & 0xFFFF));
                float v1 = b16tof((u16)(pa.x >> 16))    + b16tof((u16)(pb.x >> 16));
                float v2 = b16tof((u16)(pa.y & 0xFFFF)) + b16tof((u16)(pb.y & 0xFFFF));
                float v3 = b16tof((u16)(pa.y >> 16))    + b16tof((u16)(pb.y >> 16));
                bsum.x = pack2(v0, v1);
                bsum.y = pack2(v2, v3);
            }
            *(uint2*)&s_p[tt * 248 + 4 * l] = bsum;
        }
    }
    __syncthreads();
    // prefetch h1 frags
    const short8* ap1 = (const short8*)h1f;
    short8 a_cur[2], a_nxt[2];
    a_cur[0] = ap1[(size_t)(w * 2 + 0) * 64 + l];
    a_cur[1] = ap1[(size_t)(w * 2 + 1) * 64 + l];
    // relu(sacc + psum + skbsum) -> registers, then (after barrier) -> s_m
    unsigned rlo[2][4], rhi[2][4];
    #pragma unroll
    for (int i2 = 0; i2 < 2; i2++) {
        int m_base = (w * 2 + i2) * 16 + quad * 4;
        float4 sb4 = make_float4(0.f, 0.f, 0.f, 0.f);
        bool valid = (m_base < 240);
        if (valid) sb4 = *(const float4*)(skbsum + m_base);
        #pragma unroll
        for (int n = 0; n < 4; n++) {
            float x0 = 0.f, x1 = 0.f, x2 = 0.f, x3 = 0.f;
            if (valid) {
                uint2 pv = *(const uint2*)&s_p[(n * 16 + tloc) * 248 + m_base];
                float s0 = sacc[i2][n][0] + b16tof((u16)(pv.x & 0xFFFF));
                float s1 = sacc[i2][n][1] + b16tof((u16)(pv.x >> 16));
                float s2 = sacc[i2][n][2] + b16tof((u16)(pv.y & 0xFFFF));
                float s3 = sacc[i2][n][3] + b16tof((u16)(pv.y >> 16));
                x0 = fmaxf(s0 + sb4.x, 0.f);
                x1 = fmaxf(s1 + sb4.y, 0.f);
                x2 = fmaxf(s2 + sb4.z, 0.f);
                x3 = fmaxf(s3 + sb4.w, 0.f);
            }
            rlo[i2][n] = pack2(x0, x1);
            rhi[i2][n] = pack2(x2, x3);
        }
    }
    __syncthreads();   // all s_p reads done before overwriting as s_m
    #pragma unroll
    for (int i2 = 0; i2 < 2; i2++) {
        int m_base = (w * 2 + i2) * 16 + quad * 4;
        #pragma unroll
        for (int n = 0; n < 4; n++) {
            int tt = n * 16 + tloc;
            *(unsigned*)&s_m[tt * 264 + m_base]     = rlo[i2][n];
            *(unsigned*)&s_m[tt * 264 + m_base + 2] = rhi[i2][n];
        }
    }
    __syncthreads();
    // GEMM h1 (2 mt/wave)
    f32x4 acc[2][4];
    #pragma unroll
    for (int i = 0; i < 2; i++)
        #pragma unroll
        for (int n = 0; n < 4; n++) acc[i][n] = (f32x4){0.f, 0.f, 0.f, 0.f};
    for (int ks = 0; ks < 8; ks++) {
        if (ks < 7) {
            #pragma unroll
            for (int i = 0; i < 2; i++)
                a_nxt[i] = ap1[((size_t)(ks + 1) * 16 + w * 2 + i) * 64 + l];
        }
        short8 b[4];
        int k0 = ks * 32 + quad * 8;
        #pragma unroll
        for (int n = 0; n < 4; n++)
            b[n] = *(const short8*)&s_m[(n * 16 + tloc) * 264 + k0];
        #pragma unroll
        for (int i = 0; i < 2; i++)
            #pragma unroll
            for (int n = 0; n < 4; n++) acc[i][n] = MFMA(a_cur[i], b[n], acc[i][n]);
        #pragma unroll
        for (int i = 0; i < 2; i++) a_cur[i] = a_nxt[i];
    }
    unsigned ylo[2][4], yhi[2][4];
    #pragma unroll
    for (int i = 0; i < 2; i++) {
        int m_base = (w * 2 + i) * 16 + quad * 4;
        float4 b1 = *(const float4*)(h1_b + m_base);
        #pragma unroll
        for (int n = 0; n < 4; n++) {
            float y0 = fmaxf(acc[i][n][0] + b1.x, 0.f);
            float y1v = fmaxf(acc[i][n][1] + b1.y, 0.f);
            float y2 = fmaxf(acc[i][n][2] + b1.z, 0.f);
            float y3 = fmaxf(acc[i][n][3] + b1.w, 0.f);
            ylo[i][n] = pack2(y0, y1v);
            yhi[i][n] = pack2(y2, y3);
        }
    }
    const short8* ap2 = (const short8*)h2f;
    #pragma unroll
    for (int i = 0; i < 2; i++) a_cur[i] = ap2[(size_t)(w * 2 + i) * 64 + l];
    __syncthreads();
    #pragma unroll
    for (int i = 0; i < 2; i++) {
        int m_base = (w * 2 + i) * 16 + quad * 4;
        #pragma unroll
        for (int n = 0; n < 4; n++) {
            int t = n * 16 + tloc;
            *(unsigned*)&s_m[t * 264 + m_base]     = ylo[i][n];
            *(unsigned*)&s_m[t * 264 + m_base + 2] = yhi[i][n];
        }
    }
    __syncthreads();
    // GEMM h2
    #pragma unroll
    for (int i = 0; i < 2; i++)
        #pragma unroll
        for (int n = 0; n < 4; n++) acc[i][n] = (f32x4){0.f, 0.f, 0.f, 0.f};
    for (int ks = 0; ks < 8; ks++) {
        if (ks < 7) {
            #pragma unroll
            for (int i = 0; i < 2; i++)
                a_nxt[i] = ap2[((size_t)(ks + 1) * 16 + w * 2 + i) * 64 + l];
        }
        short8 b[4];
        int k0 = ks * 32 + quad * 8;
        #pragma unroll
        for (int n = 0; n < 4; n++)
            b[n] = *(const short8*)&s_m[(n * 16 + tloc) * 264 + k0];
        #pragma unroll
        for (int i = 0; i < 2; i++)
            #pragma unroll
            for (int n = 0; n < 4; n++) acc[i][n] = MFMA(a_cur[i], b[n], acc[i][n]);
        #pragma unroll
        for (int i = 0; i < 2; i++) a_cur[i] = a_nxt[i];
    }
    #pragma unroll
    for (int i = 0; i < 2; i++) {
        int m_base = (w * 2 + i) * 16 + quad * 4;
        float4 b2 = *(const float4*)(h2_b + m_base);
        float bb[4] = {b2.x, b2.y, b2.z, b2.w};
        #pragma unroll
        for (int n = 0; n < 4; n++) {
            int t = t0 + n * 16 + tloc;
            if (t >= L_LEN) continue;
            #pragma unroll
            for (int r = 0; r < 4; r++)
                out[(size_t)(m_base + r) * L_LEN + t] = acc[i][n][r] + bb[r];
        }
    }
}

extern "C" void kernel_launch(void* const* d_in, const int* in_sizes, int n_in,
                              void* d_out, int out_size, void* d_ws, size_t ws_size,
                              hipStream_t stream) {
    const float* wav   = (const float*)d_in[0];
    const float* mel   = (const float*)d_in[1];
    const float* up_w  = (const float*)d_in[2];
    const float* up_b  = (const float*)d_in[3];
    const float* in_w  = (const float*)d_in[4];
    const float* in_b  = (const float*)d_in[5];
    const float* bc_w  = (const float*)d_in[6];
    const float* bc_b  = (const float*)d_in[7];
    const float* bq_w  = (const float*)d_in[8];
    const float* bq_b  = (const float*)d_in[9];
    const float* bs_w  = (const float*)d_in[10];
    const float* bs_b  = (const float*)d_in[11];
    const float* br_w  = (const float*)d_in[12];
    const float* br_b  = (const float*)d_in[13];
    const float* h1_w  = (const float*)d_in[14];
    const float* h1_b  = (const float*)d_in[15];
    const float* h2_w  = (const float*)d_in[16];
    const float* h2_b  = (const float*)d_in[17];

    char* wsb = (char*)d_ws;
    const bool use_h = (ws_size >= NEED_H);

    if (use_h) {
        u16*   condT = (u16*)(wsb + H2_CONDT);
        u16*   bfA   = (u16*)(wsb + H2_BFA);
        u16*   bfB   = (u16*)(wsb + H2_BFB);
        u16*   zfrag = (u16*)(wsb + H2_ZFRAG);
        u16*   skf   = (u16*)(wsb + H2_SKF);
        u16*   rf    = (u16*)(wsb + H2_RF);
        u16*   h1f   = (u16*)(wsb + H2_H1F);
        u16*   h2f   = (u16*)(wsb + H2_H2F);
        float* zb    = (float*)(wsb + H2_ZB);
        float* skbs  = (float*)(wsb + H2_SKBS);
        u16*   hall  = (u16*)(wsb + H2_HALL);
        u16*   upf   = (u16*)(wsb + H2_HALL);   // dead after k_up; hall writes come later
        // skip partials reuse freed h slots: P0 = slots 0-1, P1 = slots 2-3
        u16*   P0    = hall;
        u16*   P1    = hall + (size_t)2 * L_LEN * 120;

        k_prep_zfrag <<<5120, 256, 0, stream>>>(bc_w, bq_w, zfrag);
        k_prep_skfrag<<<2048, 256, 0, stream>>>(bs_w, skf);
        k_prep_rfrag <<<1024, 256, 0, stream>>>(br_w, rf);
        k_prep_h1frag<<<256, 256, 0, stream>>>(h1_w, h1f);
        k_prep_h2frag<<<256, 256, 0, stream>>>(h2_w, h2f);
        k_prep_upfrag<<<25600, 256, 0, stream>>>(up_w, upf);
        k_prep_zbias <<<16, 256, 0, stream>>>(bc_b, bq_b, zb);
        k_prep_skbsum<<<1, 256, 0, stream>>>(bs_b, skbs);
        k_res_initTb <<<(L_LEN * RCH + 255) / 256, 256, 0, stream>>>(wav, in_w, in_b, bfA);
        k_up<<<dim3(256, 3), 256, 0, stream>>>(mel, upf, up_b, condT);

        u16* rin = bfA;
        u16* rout = bfB;
        // layers 0-3 fused (dils 1,2,4,8; halo 16) + in-group skip accumulation -> P0
        k_block_g4<<<NT, 512, 0, stream>>>(condT, rin, rout, P0, zfrag, skf, rf, zb, br_b, 0);
        { u16* t = rin; rin = rout; rout = t; }
        // layers 4-7 single (dils 16,32,64,128) -> h slots
        for (int i = 4; i < 8; i++) {
            k_block_h4<<<NT, 512, 0, stream>>>(condT, rin, rout,
                                               hall + (size_t)i * (size_t)L_LEN * 120,
                                               zfrag, rf, zb, br_b, i, 1 << (i & 7));
            u16* t = rin; rin = rout; rout = t;
        }
        // layers 8-11 fused -> P1
        k_block_g4<<<NT, 512, 0, stream>>>(condT, rin, rout, P1, zfrag, skf, rf, zb, br_b, 8);
        { u16* t = rin; rin = rout; rout = t; }
        // layers 12-15 single
        for (int i = 12; i < 16; i++) {
            k_block_h4<<<NT, 512, 0, stream>>>(condT, rin, rout,
                                               hall + (size_t)i * (size_t)L_LEN * 120,
                                               zfrag, rf, zb, br_b, i, 1 << (i & 7));
            u16* t = rin; rin = rout; rout = t;
        }
        k_final_h5<<<NT, 512, 0, stream>>>(hall, P0, P1, skf, h1f, h2f, skbs,
                                           h1_b, h2_b, (float*)d_out);
    } else {
        // ---- proven fallback path, byte-identical behavior ----
        u16*   condT = (u16*)(wsb + O_CONDT);
        float* resA  = (float*)(wsb + O_RESA);
        float* resB  = (float*)(wsb + O_RESB);
        u16*   skipT = (u16*)(wsb + O_SKIP);
        u16*   zfrag = (u16*)(wsb + O_ZFRAG);
        u16*   skf   = (u16*)(wsb + O_SKF);
        u16*   rf    = (u16*)(wsb + O_RF);
        u16*   h1f   = (u16*)(wsb + O_H1F);
        u16*   h2f   = (u16*)(wsb + O_H2F);
        u16*   upf   = (u16*)(wsb + O_UPF);
        float* zb    = (float*)(wsb + O_ZB);
        float* skb   = (float*)(wsb + O_SKB);

        k_prep_zfrag <<<5120, 256, 0, stream>>>(bc_w, bq_w, zfrag);
        k_prep_skfrag<<<2048, 256, 0, stream>>>(bs_w, skf);
        k_prep_rfrag <<<1024, 256, 0, stream>>>(br_w, rf);
        k_prep_h1frag<<<256, 256, 0, stream>>>(h1_w, h1f);
        k_prep_h2frag<<<256, 256, 0, stream>>>(h2_w, h2f);
        k_prep_upfrag<<<25600, 256, 0, stream>>>(up_w, upf);
        k_prep_zbias <<<16, 256, 0, stream>>>(bc_b, bq_b, zb);
        k_prep_skbias<<<15, 256, 0, stream>>>(bs_b, skb);
        k_res_initT  <<<(L_LEN * RCH + 255) / 256, 256, 0, stream>>>(wav, in_w, in_b, resA);
        k_up<<<dim3(256, 3), 256, 0, stream>>>(mel, upf, up_b, condT);

        for (int i = 0; i < NBLK; i++) {
            int d = 1 << (i & 7);
            const float* rin = (i & 1) ? resB : resA;
            float* rout      = (i & 1) ? resA : resB;
            k_block<<<NT, 512, 0, stream>>>(condT, rin, rout, skipT, zfrag, skf, rf,
                                            zb, skb, br_b, i, d, (i == 0) ? 1 : 0);
        }
        k_final<<<NT, 512, 0, stream>>>(skipT, h1f, h2f, h1_b, h2_b, (float*)d_out);
    }
}

// Round 13
// 701.371 us; speedup vs baseline: 1.0954x; 1.0954x over previous
//
#include <hip/hip_runtime.h>

#define L_LEN 39904
#define NT 624
#define RCH 120
#define SCH 240
#define CMEL 80
#define NQO 256
#define NBLK 16
#define KUP 800

typedef unsigned short u16;
typedef __attribute__((ext_vector_type(8))) short short8;
typedef __attribute__((ext_vector_type(4))) float f32x4;

#define MFMA(a, b, c) __builtin_amdgcn_mfma_f32_16x16x32_bf16((a), (b), (c), 0, 0, 0)

__device__ __forceinline__ u16 f2bf(float f) {
    unsigned u = __float_as_uint(f);
    u += 0x7FFFu + ((u >> 16) & 1u);
    return (u16)(u >> 16);
}
__device__ __forceinline__ unsigned pack2(float a, float b) {
    return (unsigned)f2bf(a) | ((unsigned)f2bf(b) << 16);
}
__device__ __forceinline__ float b16tof(u16 h) {
    return __uint_as_float((unsigned)h << 16);
}
// fast gating: tanh(a)*sigmoid(b) via v_exp + v_rcp (err ~1e-7, << bf16 noise)
__device__ __forceinline__ float gate(float a, float b) {
    float ea = __expf(2.f * a);
    float th = 1.f - 2.f * __builtin_amdgcn_rcpf(ea + 1.f);
    float sg = __builtin_amdgcn_rcpf(1.f + __expf(-b));
    return th * sg;
}

// ---- fallback ws layout ----
constexpr size_t O_CONDT = 0;
constexpr size_t O_RESA  = O_CONDT + 7023104;
constexpr size_t O_RESB  = O_RESA + 19153920;
constexpr size_t O_SKIP  = O_RESB + 19153920;
constexpr size_t O_ZFRAG = O_SKIP + 19153920;
constexpr size_t O_SKF   = O_ZFRAG + 2621440;
constexpr size_t O_RF    = O_SKF + 1048576;
constexpr size_t O_H1F   = O_RF + 524288;
constexpr size_t O_H2F   = O_H1F + 131072;
constexpr size_t O_UPF   = O_H2F + 131072;
constexpr size_t O_ZB    = O_UPF + 13107200;
constexpr size_t O_SKB   = O_ZB + 16384;

// ---- h-path layout (offsets identical to accepted r2/r4/r5/r8 runs) ----
constexpr size_t H2_CONDT = 0;                      // [L][88] bf16
constexpr size_t H2_RESF  = 7023104;                // unused slot
constexpr size_t H2_BFA   = H2_RESF + 19153920;     // [L][120] bf16
constexpr size_t H2_BFB   = H2_BFA + 9576960;       // [L][120] bf16
constexpr size_t H2_ZFRAG = H2_BFB + 9576960;
constexpr size_t H2_SKF   = H2_ZFRAG + 2621440;
constexpr size_t H2_RF    = H2_SKF + 1048576;
constexpr size_t H2_H1F   = H2_RF + 524288;
constexpr size_t H2_H2F   = H2_H1F + 131072;
constexpr size_t H2_ZB    = H2_H2F + 131072;
constexpr size_t H2_SKBS  = H2_ZB + 16384;
constexpr size_t H2_HALL  = H2_SKBS + 16384;        // h tensor / upf overlay
constexpr size_t H_BYTES  = (size_t)NBLK * L_LEN * 120 * 2;
constexpr size_t UPF_BYTES = 13107200;
constexpr size_t NEED_H = H2_HALL + (H_BYTES > UPF_BYTES ? H_BYTES : UPF_BYTES);

// ================= prep kernels =================
__global__ void k_prep_zfrag(const float* __restrict__ bc_w, const float* __restrict__ bq_w,
                             u16* __restrict__ dst) {
    int i = blockIdx.x * 256 + threadIdx.x;
    if (i >= NBLK * 10 * 16 * 512) return;
    int jj = i & 7, lane = (i >> 3) & 63, mt = (i >> 9) & 15;
    int rest = i >> 13, ks = rest % 10, blk = rest / 10;
    int m = mt * 16 + (lane & 15);
    int k = ks * 32 + ((lane >> 4) << 3) + jj;
    float v = 0.f;
    if (m < 240) {
        int o = (m & 1) ? (m >> 1) + 120 : (m >> 1);
        if (k < 120)       v = bc_w[((size_t)(blk * 240 + o) * 120 + k) * 2 + 0];
        else if (k < 240)  v = bc_w[((size_t)(blk * 240 + o) * 120 + (k - 120)) * 2 + 1];
        else               v = bq_w[(size_t)(blk * 240 + o) * 80 + (k - 240)];
    }
    dst[i] = f2bf(v);
}
__global__ void k_prep_skfrag(const float* __restrict__ bs_w, u16* __restrict__ dst) {
    int i = blockIdx.x * 256 + threadIdx.x;
    if (i >= NBLK * 4 * 16 * 512) return;
    int jj = i & 7, lane = (i >> 3) & 63, mt = (i >> 9) & 15;
    int rest = i >> 13, ks = rest & 3, blk = rest >> 2;
    int m = mt * 16 + (lane & 15);
    int k = ks * 32 + ((lane >> 4) << 3) + jj;
    float v = (m < 240 && k < 120) ? bs_w[(size_t)(blk * 240 + m) * 120 + k] : 0.f;
    dst[i] = f2bf(v);
}
__global__ void k_prep_rfrag(const float* __restrict__ br_w, u16* __restrict__ dst) {
    int i = blockIdx.x * 256 + threadIdx.x;
    if (i >= NBLK * 4 * 8 * 512) return;
    int jj = i & 7, lane = (i >> 3) & 63, mt = (i >> 9) & 7;
    int rest = i >> 12, ks = rest & 3, blk = rest >> 2;
    int m = mt * 16 + (lane & 15);
    int k = ks * 32 + ((lane >> 4) << 3) + jj;
    float v = (m < 120 && k < 120) ? br_w[(size_t)(blk * 120 + m) * 120 + k] : 0.f;
    dst[i] = f2bf(v);
}
__global__ void k_prep_h1frag(const float* __restrict__ h1_w, u16* __restrict__ dst) {
    int i = blockIdx.x * 256 + threadIdx.x;
    if (i >= 8 * 16 * 512) return;
    int jj = i & 7, lane = (i >> 3) & 63, mt = (i >> 9) & 15, ks = i >> 13;
    int m = mt * 16 + (lane & 15);
    int k = ks * 32 + ((lane >> 4) << 3) + jj;
    float v = (k < 240) ? h1_w[(size_t)m * 240 + k] : 0.f;
    dst[i] = f2bf(v);
}
__global__ void k_prep_h2frag(const float* __restrict__ h2_w, u16* __restrict__ dst) {
    int i = blockIdx.x * 256 + threadIdx.x;
    if (i >= 8 * 16 * 512) return;
    int jj = i & 7, lane = (i >> 3) & 63, mt = (i >> 9) & 15, ks = i >> 13;
    int m = mt * 16 + (lane & 15);
    int k = ks * 32 + ((lane >> 4) << 3) + jj;
    dst[i] = f2bf(h2_w[(size_t)m * 256 + k]);
}
__global__ void k_prep_upfrag(const float* __restrict__ up_w, u16* __restrict__ dst) {
    int i = blockIdx.x * 256 + threadIdx.x;
    if (i >= 256 * 10 * 5 * 512) return;
    int jj = i & 7, lane = (i >> 3) & 63;
    int rest = i >> 9;
    int mt = rest % 5; rest /= 5;
    int ks = rest % 10; int p = rest / 10;
    int m = mt * 16 + (lane & 15);
    int k = ks * 32 + ((lane >> 4) << 3) + jj;
    int c = k >> 2, j = k & 3;
    int r = (256 - ((p + 1) & 255)) & 255;
    int kk = r + 256 * j;
    float v = (m < 80 && kk < KUP) ? up_w[((size_t)m * 80 + c) * KUP + kk] : 0.f;
    dst[i] = f2bf(v);
}
__global__ void k_prep_zbias(const float* __restrict__ bc_b, const float* __restrict__ bq_b,
                             float* __restrict__ dst) {
    int i = blockIdx.x * 256 + threadIdx.x;
    if (i >= NBLK * 256) return;
    int m = i & 255, blk = i >> 8;
    float v = 0.f;
    if (m < 240) {
        int o = (m & 1) ? (m >> 1) + 120 : (m >> 1);
        v = bc_b[blk * 240 + o] + bq_b[blk * 240 + o];
    }
    dst[i] = v;
}
__global__ void k_prep_skbias(const float* __restrict__ bs_b, float* __restrict__ dst) {
    int i = blockIdx.x * 256 + threadIdx.x;
    if (i >= NBLK * 240) return;
    dst[i] = bs_b[i];
}
__global__ void k_prep_skbsum(const float* __restrict__ bs_b, float* __restrict__ dst) {
    int m = blockIdx.x * 256 + threadIdx.x;
    if (m >= 240) return;
    float s = 0.f;
    for (int i = 0; i < NBLK; i++) s += bs_b[i * 240 + m];
    dst[m] = s;
}
__global__ void k_res_initT(const float* __restrict__ wav, const float* __restrict__ in_w,
                            const float* __restrict__ in_b, float* __restrict__ resT) {
    int i = blockIdx.x * 256 + threadIdx.x;
    if (i >= L_LEN * RCH) return;
    int t = i / RCH, c = i % RCH;
    resT[i] = wav[t] * in_w[c] + in_b[c];
}
// h-path: bf16 res carrier only
__global__ void k_res_initTb(const float* __restrict__ wav, const float* __restrict__ in_w,
                             const float* __restrict__ in_b, u16* __restrict__ resB) {
    int i = blockIdx.x * 256 + threadIdx.x;
    if (i >= L_LEN * RCH) return;
    int t = i / RCH, c = i % RCH;
    resB[i] = f2bf(wav[t] * in_w[c] + in_b[c]);
}

// ================= upsample (MFMA, per phase p) =================
__global__ __launch_bounds__(256) void k_up(const float* __restrict__ mel,
        const u16* __restrict__ upf, const float* __restrict__ up_b,
        u16* __restrict__ condT) {
    __shared__ u16 s_ms[64 * 328];
    const int tid = threadIdx.x, l = tid & 63, w = tid >> 6;
    const int quad = l >> 4, tloc = l & 15;
    const int p = blockIdx.x, s0 = blockIdx.y * 64;
    for (int rr = 0; rr < 16; rr++) {
        int tt = w + 4 * rr;
        int sg = s0 + tt;
        #pragma unroll
        for (int base = 0; base < 320; base += 64) {
            int ck = base + l;
            int c = ck >> 2, j = ck & 3;
            int mi = 1 + j + sg;
            float v = (mi < 160) ? mel[c * 160 + mi] : 0.f;
            s_ms[tt * 328 + ck] = f2bf(v);
        }
    }
    __syncthreads();
    f32x4 acc[2][4];
    #pragma unroll
    for (int i = 0; i < 2; i++)
        #pragma unroll
        for (int n = 0; n < 4; n++) acc[i][n] = (f32x4){0.f, 0.f, 0.f, 0.f};
    const int nmt = (w == 0) ? 2 : 1;
    int mts[2]; mts[0] = w; mts[1] = 4;
    for (int ks = 0; ks < 10; ks++) {
        short8 b[4];
        int k0 = ks * 32 + quad * 8;
        #pragma unroll
        for (int n = 0; n < 4; n++)
            b[n] = *(const short8*)&s_ms[(n * 16 + tloc) * 328 + k0];
        const short8* ap = (const short8*)(upf) + ((size_t)p * 10 + ks) * 5 * 64;
        for (int i = 0; i < nmt; i++) {
            short8 a = ap[mts[i] * 64 + l];
            #pragma unroll
            for (int n = 0; n < 4; n++) acc[i][n] = MFMA(a, b[n], acc[i][n]);
        }
    }
    for (int i = 0; i < nmt; i++) {
        int o_base = mts[i] * 16 + quad * 4;
        float4 ub = *(const float4*)(up_b + o_base);
        float bb[4] = {ub.x, ub.y, ub.z, ub.w};
        #pragma unroll
        for (int n = 0; n < 4; n++) {
            int sg = s0 + n * 16 + tloc;
            int t = p + 256 * sg;
            if (t < L_LEN) {
                #pragma unroll
                for (int r = 0; r < 4; r++)
                    condT[(size_t)t * 88 + o_base + r] = f2bf(acc[i][n][r] + bb[r]);
            }
        }
    }
}

// ================= WaveNet block — FALLBACK (proven path, unchanged) =================
__global__ __launch_bounds__(512, 4) void k_block(
        const u16* __restrict__ condT, const float* __restrict__ resT_in,
        float* __restrict__ resT_out, u16* __restrict__ skipT,
        const u16* __restrict__ zfrag, const u16* __restrict__ skfrag,
        const u16* __restrict__ rfrag, const float* __restrict__ zbias,
        const float* __restrict__ skbias, const float* __restrict__ resb,
        int blk, int dil, int first) {
    __shared__ u16 s_x[64 * 328];
    u16* s_h = s_x;
    const int tid = threadIdx.x, l = tid & 63, w = tid >> 6;
    const int quad = l >> 4, tloc = l & 15;
    const int t0 = blockIdx.x * 64;
    const short8* zap = (const short8*)(zfrag) + (size_t)blk * 10 * 16 * 64;
    short8 a_cur[2], a_nxt[2];
    #pragma unroll
    for (int i = 0; i < 2; i++) a_cur[i] = zap[(size_t)(w * 2 + i) * 64 + l];
    for (int rr = 0; rr < 8; rr++) {
        int tt = w + 8 * rr;
        int tg = t0 + tt, tp = tg - dil;
        if (l < 60) {
            float2 pv = make_float2(0.f, 0.f), cv = make_float2(0.f, 0.f);
            if (tp >= 0 && tp < L_LEN) pv = *(const float2*)(resT_in + (size_t)tp * 120 + 2 * l);
            if (tg < L_LEN)            cv = *(const float2*)(resT_in + (size_t)tg * 120 + 2 * l);
            *(unsigned*)&s_x[tt * 328 + 2 * l]       = pack2(pv.x, pv.y);
            *(unsigned*)&s_x[tt * 328 + 120 + 2 * l] = pack2(cv.x, cv.y);
        }
        if (l < 40) {
            unsigned q = 0;
            if (tg < L_LEN) q = *(const unsigned*)(condT + (size_t)tg * 88 + 2 * l);
            *(unsigned*)&s_x[tt * 328 + 240 + 2 * l] = q;
        }
    }
    __syncthreads();
    f32x4 acc[2][4];
    #pragma unroll
    for (int i = 0; i < 2; i++)
        #pragma unroll
        for (int n = 0; n < 4; n++) acc[i][n] = (f32x4){0.f, 0.f, 0.f, 0.f};
    for (int ks = 0; ks < 10; ks++) {
        if (ks < 9) {
            #pragma unroll
            for (int i = 0; i < 2; i++)
                a_nxt[i] = zap[((size_t)(ks + 1) * 16 + w * 2 + i) * 64 + l];
        }
        int k0 = ks * 32 + quad * 8;
        short8 b[4];
        #pragma unroll
        for (int n = 0; n < 4; n++)
            b[n] = *(const short8*)&s_x[(n * 16 + tloc) * 328 + k0];
        #pragma unroll
        for (int i = 0; i < 2; i++)
            #pragma unroll
            for (int n = 0; n < 4; n++) acc[i][n] = MFMA(a_cur[i], b[n], acc[i][n]);
        #pragma unroll
        for (int i = 0; i < 2; i++) a_cur[i] = a_nxt[i];
    }
    const short8* sap = (const short8*)(skfrag) + (size_t)blk * 4 * 16 * 64;
    const short8* rap = (const short8*)(rfrag) + (size_t)blk * 4 * 8 * 64;
    short8 sa_c[2], sa_n[2], ra_c, ra_n;
    #pragma unroll
    for (int i = 0; i < 2; i++) sa_c[i] = sap[(size_t)(w * 2 + i) * 64 + l];
    ra_c = rap[(size_t)w * 64 + l];
    uint2 skp[2][4];
    if (!first) {
        #pragma unroll
        for (int i = 0; i < 2; i++) {
            int m_base = (w * 2 + i) * 16 + quad * 4;
            if (m_base < 240) {
                #pragma unroll
                for (int n = 0; n < 4; n++) {
                    int t = t0 + n * 16 + tloc;
                    if (t < L_LEN)
                        skp[i][n] = *(const uint2*)(skipT + (size_t)t * 240 + m_base);
                }
            }
        }
    }
    unsigned hu[2][4];
    #pragma unroll
    for (int i = 0; i < 2; i++) {
        int m_base = (w * 2 + i) * 16 + quad * 4;
        float4 bz4 = *(const float4*)(zbias + blk * 256 + m_base);
        #pragma unroll
        for (int n = 0; n < 4; n++) {
            float h0 = gate(acc[i][n][0] + bz4.x, acc[i][n][1] + bz4.y);
            float h1 = gate(acc[i][n][2] + bz4.z, acc[i][n][3] + bz4.w);
            hu[i][n] = pack2(h0, h1);
        }
    }
    __syncthreads();
    #pragma unroll
    for (int i = 0; i < 2; i++) {
        int j0 = (w * 2 + i) * 8 + quad * 2;
        #pragma unroll
        for (int n = 0; n < 4; n++)
            *(unsigned*)&s_h[(n * 16 + tloc) * 136 + j0] = hu[i][n];
    }
    __syncthreads();
    f32x4 sacc[2][4], racc[4];
    #pragma unroll
    for (int i = 0; i < 2; i++)
        #pragma unroll
        for (int n = 0; n < 4; n++) sacc[i][n] = (f32x4){0.f, 0.f, 0.f, 0.f};
    #pragma unroll
    for (int n = 0; n < 4; n++) racc[n] = (f32x4){0.f, 0.f, 0.f, 0.f};
    for (int ks = 0; ks < 4; ks++) {
        if (ks < 3) {
            #pragma unroll
            for (int i = 0; i < 2; i++)
                sa_n[i] = sap[((size_t)(ks + 1) * 16 + w * 2 + i) * 64 + l];
            ra_n = rap[((size_t)(ks + 1) * 8 + w) * 64 + l];
        }
        short8 b[4];
        int k0 = ks * 32 + quad * 8;
        #pragma unroll
        for (int n = 0; n < 4; n++)
            b[n] = *(const short8*)&s_h[(n * 16 + tloc) * 136 + k0];
        #pragma unroll
        for (int i = 0; i < 2; i++)
            #pragma unroll
            for (int n = 0; n < 4; n++) sacc[i][n] = MFMA(sa_c[i], b[n], sacc[i][n]);
        #pragma unroll
        for (int n = 0; n < 4; n++) racc[n] = MFMA(ra_c, b[n], racc[n]);
        #pragma unroll
        for (int i = 0; i < 2; i++) sa_c[i] = sa_n[i];
        ra_c = ra_n;
    }
    #pragma unroll
    for (int i = 0; i < 2; i++) {
        int m_base = (w * 2 + i) * 16 + quad * 4;
        if (m_base >= 240) continue;
        float4 sb4 = *(const float4*)(skbias + blk * 240 + m_base);
        #pragma unroll
        for (int n = 0; n < 4; n++) {
            int t = t0 + n * 16 + tloc;
            if (t >= L_LEN) continue;
            float x0 = sacc[i][n][0] + sb4.x;
            float x1 = sacc[i][n][1] + sb4.y;
            float x2 = sacc[i][n][2] + sb4.z;
            float x3 = sacc[i][n][3] + sb4.w;
            if (!first) {
                uint2 pv = skp[i][n];
                x0 += b16tof((u16)(pv.x & 0xFFFF));
                x1 += b16tof((u16)(pv.x >> 16));
                x2 += b16tof((u16)(pv.y & 0xFFFF));
                x3 += b16tof((u16)(pv.y >> 16));
            }
            uint2 ov;
            ov.x = pack2(x0, x1);
            ov.y = pack2(x2, x3);
            *(uint2*)(skipT + (size_t)t * 240 + m_base) = ov;
        }
    }
    {
        int m_base = w * 16 + quad * 4;
        if (m_base < 120) {
            float4 rb4 = *(const float4*)(resb + blk * 120 + m_base);
            #pragma unroll
            for (int n = 0; n < 4; n++) {
                int t = t0 + n * 16 + tloc;
                if (t >= L_LEN) continue;
                float4 cur = *(const float4*)(resT_in + (size_t)t * 120 + m_base);
                float4 o;
                o.x = cur.x + racc[n][0] + rb4.x;
                o.y = cur.y + racc[n][1] + rb4.y;
                o.z = cur.z + racc[n][2] + rb4.z;
                o.w = cur.w + racc[n][3] + rb4.w;
                *(float4*)(resT_out + (size_t)t * 120 + m_base) = o;
            }
        }
    }
}

// ===== single-layer WaveNet block (r5/r8 proven, dil>=16): bf16 carrier, LDS past-copy =====
__global__ __launch_bounds__(512, 4) void k_block_h4(
        const u16* __restrict__ condT,
        const u16* __restrict__ bfIn, u16* __restrict__ bfOut,
        u16* __restrict__ hout,
        const u16* __restrict__ zfrag, const u16* __restrict__ rfrag,
        const float* __restrict__ zbias, const float* __restrict__ resb,
        int blk, int dil) {
    __shared__ u16 s_x[64 * 328];
    u16* s_h = s_x;
    const int tid = threadIdx.x, l = tid & 63, w = tid >> 6;
    const int quad = l >> 4, tloc = l & 15;
    const int t0 = blockIdx.x * 64;
    const short8* zap = (const short8*)(zfrag) + (size_t)blk * 10 * 16 * 64;
    short8 a_cur[2], a_nxt[2];
    a_cur[0] = zap[(size_t)(w * 2 + 0) * 64 + l];
    a_cur[1] = zap[(size_t)(w * 2 + 1) * 64 + l];
    const uint2 Z2 = make_uint2(0u, 0u);
    for (int rr = 0; rr < 8; rr++) {
        int tt = w + 8 * rr, tg = t0 + tt;
        if (l < 30) {
            uint2 cv = (tg < L_LEN) ? *(const uint2*)(bfIn + (size_t)tg * 120 + 4 * l) : Z2;
            *(uint2*)&s_x[tt * 328 + 120 + 4 * l] = cv;
            if (tt < dil) {
                int tp = tg - dil;
                uint2 pv = (tp >= 0 && tp < L_LEN)
                    ? *(const uint2*)(bfIn + (size_t)tp * 120 + 4 * l) : Z2;
                *(uint2*)&s_x[tt * 328 + 4 * l] = pv;
            }
        } else if (l >= 32 && l < 54) {
            int c = l - 32;
            uint2 q = (tg < L_LEN) ? *(const uint2*)(condT + (size_t)tg * 88 + 4 * c) : Z2;
            *(uint2*)&s_x[tt * 328 + 240 + 4 * c] = q;
        }
    }
    __syncthreads();
    if (dil < 64) {
        for (int rr = 0; rr < 8; rr++) {
            int tt = w + 8 * rr;
            if (l < 30 && tt >= dil)
                *(uint2*)&s_x[tt * 328 + 4 * l] =
                    *(const uint2*)&s_x[(tt - dil) * 328 + 120 + 4 * l];
        }
        __syncthreads();
    }
    f32x4 acc[2][4];
    #pragma unroll
    for (int i = 0; i < 2; i++)
        #pragma unroll
        for (int n = 0; n < 4; n++) acc[i][n] = (f32x4){0.f, 0.f, 0.f, 0.f};
    for (int ks = 0; ks < 10; ks++) {
        if (ks < 9) {
            a_nxt[0] = zap[((size_t)(ks + 1) * 16 + w * 2 + 0) * 64 + l];
            a_nxt[1] = zap[((size_t)(ks + 1) * 16 + w * 2 + 1) * 64 + l];
        }
        int k0 = ks * 32 + quad * 8;
        short8 b[4];
        #pragma unroll
        for (int n = 0; n < 4; n++)
            b[n] = *(const short8*)&s_x[(n * 16 + tloc) * 328 + k0];
        #pragma unroll
        for (int i = 0; i < 2; i++)
            #pragma unroll
            for (int n = 0; n < 4; n++) acc[i][n] = MFMA(a_cur[i], b[n], acc[i][n]);
        a_cur[0] = a_nxt[0]; a_cur[1] = a_nxt[1];
    }
    const short8* rap = (const short8*)(rfrag) + (size_t)blk * 4 * 8 * 64;
    short8 ra_c = rap[(size_t)w * 64 + l], ra_n;
    const int m_r = w * 16 + quad * 4;
    uint2 curb[4];
    if (m_r < 120) {
        #pragma unroll
        for (int n = 0; n < 4; n++)
            curb[n] = *(const uint2*)&s_x[(n * 16 + tloc) * 328 + 120 + m_r];
    }
    unsigned hu[2][4];
    #pragma unroll
    for (int i = 0; i < 2; i++) {
        int m_base = (w * 2 + i) * 16 + quad * 4;
        float4 bz4 = *(const float4*)(zbias + blk * 256 + m_base);
        #pragma unroll
        for (int n = 0; n < 4; n++) {
            float h0 = gate(acc[i][n][0] + bz4.x, acc[i][n][1] + bz4.y);
            float h1 = gate(acc[i][n][2] + bz4.z, acc[i][n][3] + bz4.w);
            hu[i][n] = pack2(h0, h1);
        }
    }
    __syncthreads();
    #pragma unroll
    for (int i = 0; i < 2; i++) {
        int j0 = (w * 2 + i) * 8 + quad * 2;
        #pragma unroll
        for (int n = 0; n < 4; n++)
            *(unsigned*)&s_h[(n * 16 + tloc) * 136 + j0] = hu[i][n];
    }
    __syncthreads();
    for (int rr = 0; rr < 8; rr++) {
        int tt = w + 8 * rr, tg = t0 + tt;
        if (l < 60 && tg < L_LEN)
            *(unsigned*)&hout[(size_t)tg * 120 + 2 * l] =
                *(const unsigned*)&s_h[tt * 136 + 2 * l];
    }
    f32x4 racc[4];
    #pragma unroll
    for (int n = 0; n < 4; n++) racc[n] = (f32x4){0.f, 0.f, 0.f, 0.f};
    for (int ks = 0; ks < 4; ks++) {
        if (ks < 3) ra_n = rap[((size_t)(ks + 1) * 8 + w) * 64 + l];
        short8 b[4];
        int k0 = ks * 32 + quad * 8;
        #pragma unroll
        for (int n = 0; n < 4; n++)
            b[n] = *(const short8*)&s_h[(n * 16 + tloc) * 136 + k0];
        #pragma unroll
        for (int n = 0; n < 4; n++) racc[n] = MFMA(ra_c, b[n], racc[n]);
        ra_c = ra_n;
    }
    if (m_r < 120) {
        float4 rb4 = *(const float4*)(resb + blk * 120 + m_r);
        #pragma unroll
        for (int n = 0; n < 4; n++) {
            int t = t0 + n * 16 + tloc;
            if (t >= L_LEN) continue;
            float o0 = b16tof((u16)(curb[n].x & 0xFFFF)) + racc[n][0] + rb4.x;
            float o1 = b16tof((u16)(curb[n].x >> 16))    + racc[n][1] + rb4.y;
            float o2 = b16tof((u16)(curb[n].y & 0xFFFF)) + racc[n][2] + rb4.z;
            float o3 = b16tof((u16)(curb[n].y >> 16))    + racc[n][3] + rb4.w;
            uint2 hv;
            hv.x = pack2(o0, o1);
            hv.y = pack2(o2, o3);
            *(uint2*)(bfOut + (size_t)t * 120 + m_r) = hv;
        }
    }
}

// ===== 4-layer group kernel for dils (1,2,4,8). Halo 16; res lives in LDS (r8 proven) =====
__global__ __launch_bounds__(512, 4) void k_block_g4(
        const u16* __restrict__ condT,
        const u16* __restrict__ bfIn, u16* __restrict__ bfOut,
        u16* __restrict__ hall,
        const u16* __restrict__ zfrag, const u16* __restrict__ rfrag,
        const float* __restrict__ zbias, const float* __restrict__ resb,
        int base) {
    __shared__ u16 s_res[80 * 120];   // 19200 B
    __shared__ u16 s_cond[80 * 88];   // 14080 B
    __shared__ u16 s_h[80 * 136];     // 21760 B  (total 55040 B -> 2 blocks/CU)
    const int tid = threadIdx.x, l = tid & 63, w = tid >> 6;
    const int quad = l >> 4, tloc = l & 15;
    const int t0 = blockIdx.x * 64;
    const uint2 Z2 = make_uint2(0u, 0u);
    // ---- stage 80 rows [t0-16, t0+64) of res (bf16) + cond ----
    for (int rr = 0; rr < 10; rr++) {
        int row = w + 8 * rr;
        int tg = t0 - 16 + row;
        bool ok = (tg >= 0 && tg < L_LEN);
        if (l < 30) {
            uint2 v = ok ? *(const uint2*)(bfIn + (size_t)tg * 120 + 4 * l) : Z2;
            *(uint2*)&s_res[row * 120 + 4 * l] = v;
        } else if (l >= 32 && l < 54) {
            int c = l - 32;
            uint2 q = ok ? *(const uint2*)(condT + (size_t)tg * 88 + 4 * c) : Z2;
            *(uint2*)&s_cond[row * 88 + 4 * c] = q;
        }
    }
    __syncthreads();
    const int m_r = w * 16 + quad * 4;
    for (int k = 0; k < 4; k++) {
        const int blk = base + k;
        const int d = 1 << k;                    // 1,2,4,8
        const short8* zap = (const short8*)(zfrag) + (size_t)blk * 10 * 16 * 64;
        const short8* rap = (const short8*)(rfrag) + (size_t)blk * 4 * 8 * 64;
        u16* hout = hall + (size_t)blk * ((size_t)L_LEN * 120);
        short8 a_cur[2], a_nxt[2];
        a_cur[0] = zap[(size_t)(w * 2 + 0) * 64 + l];
        a_cur[1] = zap[(size_t)(w * 2 + 1) * 64 + l];
        // ---- z GEMM: M=256 (2 mt/wave), K=320, N=80 (5 col-frags) ----
        f32x4 acc[2][5];
        #pragma unroll
        for (int i = 0; i < 2; i++)
            #pragma unroll
            for (int n = 0; n < 5; n++) acc[i][n] = (f32x4){0.f, 0.f, 0.f, 0.f};
        for (int ks = 0; ks < 10; ks++) {
            if (ks < 9) {
                a_nxt[0] = zap[((size_t)(ks + 1) * 16 + w * 2 + 0) * 64 + l];
                a_nxt[1] = zap[((size_t)(ks + 1) * 16 + w * 2 + 1) * 64 + l];
            }
            int k0 = ks * 32 + quad * 8;
            short8 b[5];
            #pragma unroll
            for (int n = 0; n < 5; n++) {
                int r = n * 16 + tloc;
                const u16* src;
                if (k0 < 120) {
                    int pr = r - d; if (pr < 0) pr = 0;   // clamped rows are invalid anyway
                    src = &s_res[pr * 120 + k0];
                } else if (k0 < 240) {
                    src = &s_res[r * 120 + (k0 - 120)];
                } else {
                    src = &s_cond[r * 88 + (k0 - 240)];
                }
                b[n] = *(const short8*)src;
            }
            #pragma unroll
            for (int i = 0; i < 2; i++)
                #pragma unroll
                for (int n = 0; n < 5; n++) acc[i][n] = MFMA(a_cur[i], b[n], acc[i][n]);
            a_cur[0] = a_nxt[0]; a_cur[1] = a_nxt[1];
        }
        // ---- gating ----
        unsigned hu[2][5];
        #pragma unroll
        for (int i = 0; i < 2; i++) {
            int m_base = (w * 2 + i) * 16 + quad * 4;
            float4 bz4 = *(const float4*)(zbias + blk * 256 + m_base);
            #pragma unroll
            for (int n = 0; n < 5; n++) {
                float h0 = gate(acc[i][n][0] + bz4.x, acc[i][n][1] + bz4.y);
                float h1 = gate(acc[i][n][2] + bz4.z, acc[i][n][3] + bz4.w);
                hu[i][n] = pack2(h0, h1);
            }
        }
        // ---- h transpose into s_h (free since prev layer's barrier) ----
        #pragma unroll
        for (int i = 0; i < 2; i++) {
            int j0 = (w * 2 + i) * 8 + quad * 2;
            #pragma unroll
            for (int n = 0; n < 5; n++)
                *(unsigned*)&s_h[(n * 16 + tloc) * 136 + j0] = hu[i][n];
        }
        __syncthreads();   // s_h ready; all z reads of s_res complete
        // ---- h global write (rows 16..79 = [t0, t0+64)) ----
        for (int rr = 0; rr < 8; rr++) {
            int row = 16 + w + 8 * rr;
            int tg = t0 + w + 8 * rr;
            if (l < 60 && tg < L_LEN)
                *(unsigned*)&hout[(size_t)tg * 120 + 2 * l] =
                    *(const unsigned*)&s_h[row * 136 + 2 * l];
        }
        // ---- res GEMM (1 mt/wave), K=128, N=80 ----
        f32x4 racc[5];
        #pragma unroll
        for (int n = 0; n < 5; n++) racc[n] = (f32x4){0.f, 0.f, 0.f, 0.f};
        short8 ra_c = rap[(size_t)w * 64 + l], ra_n;
        for (int ks = 0; ks < 4; ks++) {
            if (ks < 3) ra_n = rap[((size_t)(ks + 1) * 8 + w) * 64 + l];
            short8 b[5];
            int k0 = ks * 32 + quad * 8;
            #pragma unroll
            for (int n = 0; n < 5; n++)
                b[n] = *(const short8*)&s_h[(n * 16 + tloc) * 136 + k0];
            #pragma unroll
            for (int n = 0; n < 5; n++) racc[n] = MFMA(ra_c, b[n], racc[n]);
            ra_c = ra_n;
        }
        // ---- in-place res update (skip tglob<0: keep zero-padding; each elem 1 owner) ----
        if (m_r < 120) {
            float4 rb4 = *(const float4*)(resb + blk * 120 + m_r);
            #pragma unroll
            for (int n = 0; n < 5; n++) {
                int row = n * 16 + tloc;
                int tg = t0 - 16 + row;
                if (tg < 0 || tg >= L_LEN) continue;
                uint2 cv = *(const uint2*)&s_res[row * 120 + m_r];
                float o0 = b16tof((u16)(cv.x & 0xFFFF)) + racc[n][0] + rb4.x;
                float o1 = b16tof((u16)(cv.x >> 16))    + racc[n][1] + rb4.y;
                float o2 = b16tof((u16)(cv.y & 0xFFFF)) + racc[n][2] + rb4.z;
                float o3 = b16tof((u16)(cv.y >> 16))    + racc[n][3] + rb4.w;
                uint2 hv;
                hv.x = pack2(o0, o1);
                hv.y = pack2(o2, o3);
                *(uint2*)&s_res[row * 120 + m_r] = hv;
            }
        }
        __syncthreads();   // s_res updated + s_h reads done before next layer
    }
    // ---- write final res (layer base+3 output) rows 16..79 to bfOut ----
    for (int rr = 0; rr < 8; rr++) {
        int row = 16 + w + 8 * rr;
        int tg = t0 + w + 8 * rr;
        if (l < 30 && tg < L_LEN)
            *(uint2*)(bfOut + (size_t)tg * 120 + 4 * l) =
                *(const uint2*)&s_res[row * 120 + 4 * l];
    }
}

// ================= head — FALLBACK (unchanged) =================
__global__ __launch_bounds__(512, 4) void k_final(const u16* __restrict__ skipT,
        const u16* __restrict__ h1f, const u16* __restrict__ h2f,
        const float* __restrict__ h1_b, const float* __restrict__ h2_b,
        float* __restrict__ out) {
    __shared__ u16 s_m[64 * 264];
    const int tid = threadIdx.x, l = tid & 63, w = tid >> 6;
    const int quad = l >> 4, tloc = l & 15;
    const int t0 = blockIdx.x * 64;
    const short8* ap1 = (const short8*)h1f;
    short8 a_cur[2], a_nxt[2];
    #pragma unroll
    for (int i = 0; i < 2; i++) a_cur[i] = ap1[(size_t)(w * 2 + i) * 64 + l];
    for (int rr = 0; rr < 8; rr++) {
        int tt = w + 8 * rr;
        int tg = t0 + tt;
        uint2 v = make_uint2(0u, 0u);
        if (l < 60 && tg < L_LEN)
            v = *(const uint2*)(skipT + (size_t)tg * 240 + 4 * l);
        float x0 = fmaxf(b16tof((u16)(v.x & 0xFFFF)), 0.f);
        float x1 = fmaxf(b16tof((u16)(v.x >> 16)), 0.f);
        float x2 = fmaxf(b16tof((u16)(v.y & 0xFFFF)), 0.f);
        float x3 = fmaxf(b16tof((u16)(v.y >> 16)), 0.f);
        uint2 ov;
        ov.x = pack2(x0, x1);
        ov.y = pack2(x2, x3);
        *(uint2*)&s_m[tt * 264 + 4 * l] = ov;
    }
    __syncthreads();
    f32x4 acc[2][4];
    #pragma unroll
    for (int i = 0; i < 2; i++)
        #pragma unroll
        for (int n = 0; n < 4; n++) acc[i][n] = (f32x4){0.f, 0.f, 0.f, 0.f};
    for (int ks = 0; ks < 8; ks++) {
        if (ks < 7) {
            #pragma unroll
            for (int i = 0; i < 2; i++)
                a_nxt[i] = ap1[((size_t)(ks + 1) * 16 + w * 2 + i) * 64 + l];
        }
        short8 b[4];
        int k0 = ks * 32 + quad * 8;
        #pragma unroll
        for (int n = 0; n < 4; n++)
            b[n] = *(const short8*)&s_m[(n * 16 + tloc) * 264 + k0];
        #pragma unroll
        for (int i = 0; i < 2; i++)
            #pragma unroll
            for (int n = 0; n < 4; n++) acc[i][n] = MFMA(a_cur[i], b[n], acc[i][n]);
        #pragma unroll
        for (int i = 0; i < 2; i++) a_cur[i] = a_nxt[i];
    }
    unsigned ylo[2][4], yhi[2][4];
    #pragma unroll
    for (int i = 0; i < 2; i++) {
        int m_base = (w * 2 + i) * 16 + quad * 4;
        float4 b1 = *(const float4*)(h1_b + m_base);
        #pragma unroll
        for (int n = 0; n < 4; n++) {
            float y0 = fmaxf(acc[i][n][0] + b1.x, 0.f);
            float y1v = fmaxf(acc[i][n][1] + b1.y, 0.f);
            float y2 = fmaxf(acc[i][n][2] + b1.z, 0.f);
            float y3 = fmaxf(acc[i][n][3] + b1.w, 0.f);
            ylo[i][n] = pack2(y0, y1v);
            yhi[i][n] = pack2(y2, y3);
        }
    }
    const short8* ap2 = (const short8*)h2f;
    #pragma unroll
    for (int i = 0; i < 2; i++) a_cur[i] = ap2[(size_t)(w * 2 + i) * 64 + l];
    __syncthreads();
    #pragma unroll
    for (int i = 0; i < 2; i++) {
        int m_base = (w * 2 + i) * 16 + quad * 4;
        #pragma unroll
        for (int n = 0; n < 4; n++) {
            int t = n * 16 + tloc;
            *(unsigned*)&s_m[t * 264 + m_base]     = ylo[i][n];
            *(unsigned*)&s_m[t * 264 + m_base + 2] = yhi[i][n];
        }
    }
    __syncthreads();
    #pragma unroll
    for (int i = 0; i < 2; i++)
        #pragma unroll
        for (int n = 0; n < 4; n++) acc[i][n] = (f32x4){0.f, 0.f, 0.f, 0.f};
    for (int ks = 0; ks < 8; ks++) {
        if (ks < 7) {
            #pragma unroll
            for (int i = 0; i < 2; i++)
                a_nxt[i] = ap2[((size_t)(ks + 1) * 16 + w * 2 + i) * 64 + l];
        }
        short8 b[4];
        int k0 = ks * 32 + quad * 8;
        #pragma unroll
        for (int n = 0; n < 4; n++)
            b[n] = *(const short8*)&s_m[(n * 16 + tloc) * 264 + k0];
        #pragma unroll
        for (int i = 0; i < 2; i++)
            #pragma unroll
            for (int n = 0; n < 4; n++) acc[i][n] = MFMA(a_cur[i], b[n], acc[i][n]);
        #pragma unroll
        for (int i = 0; i < 2; i++) a_cur[i] = a_nxt[i];
    }
    #pragma unroll
    for (int i = 0; i < 2; i++) {
        int m_base = (w * 2 + i) * 16 + quad * 4;
        float4 b2 = *(const float4*)(h2_b + m_base);
        float bb[4] = {b2.x, b2.y, b2.z, b2.w};
        #pragma unroll
        for (int n = 0; n < 4; n++) {
            int t = t0 + n * 16 + tloc;
            if (t >= L_LEN) continue;
            #pragma unroll
            for (int r = 0; r < 4; r++)
                out[(size_t)(m_base + r) * L_LEN + t] = acc[i][n][r] + bb[r];
        }
    }
}

// ===== head v3 (r8 proven): double-buffered LDS + 2-deep h prefetch =====
__global__ __launch_bounds__(512, 4) void k_final_h3(const u16* __restrict__ hall,
        const u16* __restrict__ skf, const u16* __restrict__ h1f,
        const u16* __restrict__ h2f, const float* __restrict__ skbsum,
        const float* __restrict__ h1_b, const float* __restrict__ h2_b,
        float* __restrict__ out) {
    __shared__ u16 smem[2 * 64 * 136];   // 34816 B; h1/h2 phase needs 33792 B
    u16* s_m = smem;                     // stride-264 alias for h1/h2 phase
    const int tid = threadIdx.x, l = tid & 63, w = tid >> 6;
    const int quad = l >> 4, tloc = l & 15;
    const int t0 = blockIdx.x * 64;
    const short8* sap = (const short8*)skf;

    unsigned ha[8], hb[8];
    auto LOADH = [&](unsigned (&reg)[8], int i) {
        const u16* hp = hall + (size_t)i * ((size_t)L_LEN * 120);
        #pragma unroll
        for (int rr = 0; rr < 8; rr++) {
            int tg = t0 + w + 8 * rr;
            reg[rr] = (l < 60 && tg < L_LEN)
                ? *(const unsigned*)&hp[(size_t)tg * 120 + 2 * l] : 0u;
        }
    };
    // zero pad cols 120..127 of BOTH buffers once
    if (l >= 60) {
        #pragma unroll
        for (int rr = 0; rr < 8; rr++) {
            int row = w + 8 * rr;
            *(unsigned*)&smem[row * 136 + 2 * l] = 0u;
            *(unsigned*)&smem[64 * 136 + row * 136 + 2 * l] = 0u;
        }
    }
    LOADH(ha, 0);
    #pragma unroll
    for (int rr = 0; rr < 8; rr++)
        if (l < 60) *(unsigned*)&smem[(w + 8 * rr) * 136 + 2 * l] = ha[rr];
    LOADH(hb, 1);
    short8 sa_c[2], sa_n[2];
    sa_c[0] = sap[(size_t)(w * 2 + 0) * 64 + l];
    sa_c[1] = sap[(size_t)(w * 2 + 1) * 64 + l];
    f32x4 sacc[2][4];
    #pragma unroll
    for (int i = 0; i < 2; i++)
        #pragma unroll
        for (int n = 0; n < 4; n++) sacc[i][n] = (f32x4){0.f, 0.f, 0.f, 0.f};
    __syncthreads();
    // 16 steps, ONE barrier each: GEMM h_i from buf[i&1] while writing h_{i+1}
    // into buf[(i+1)&1] and loading h_{i+2} into the freed register set.
    #pragma unroll
    for (int i = 0; i < 16; i++) {
        u16* cur = smem + (i & 1) * (64 * 136);
        u16* nxt = smem + ((i + 1) & 1) * (64 * 136);
        unsigned (&wrg)[8] = (i & 1) ? ha : hb;   // holds h_{i+1}
        unsigned (&lrg)[8] = (i & 1) ? hb : ha;   // target for h_{i+2}
        if (i < 15) {
            #pragma unroll
            for (int rr = 0; rr < 8; rr++)
                if (l < 60) *(unsigned*)&nxt[(w + 8 * rr) * 136 + 2 * l] = wrg[rr];
        }
        if (i < 14) LOADH(lrg, i + 2);
        for (int ks = 0; ks < 4; ks++) {
            int g = i * 4 + ks;
            if (g < 63) {
                sa_n[0] = sap[((size_t)(g + 1) * 16 + w * 2 + 0) * 64 + l];
                sa_n[1] = sap[((size_t)(g + 1) * 16 + w * 2 + 1) * 64 + l];
            }
            int k0 = ks * 32 + quad * 8;
            short8 b[4];
            #pragma unroll
            for (int n = 0; n < 4; n++)
                b[n] = *(const short8*)&cur[(n * 16 + tloc) * 136 + k0];
            #pragma unroll
            for (int i2 = 0; i2 < 2; i2++)
                #pragma unroll
                for (int n = 0; n < 4; n++)
                    sacc[i2][n] = MFMA(sa_c[i2], b[n], sacc[i2][n]);
            sa_c[0] = sa_n[0]; sa_c[1] = sa_n[1];
        }
        __syncthreads();
    }
    // prefetch h1 frags
    const short8* ap1 = (const short8*)h1f;
    short8 a_cur[2], a_nxt[2];
    a_cur[0] = ap1[(size_t)(w * 2 + 0) * 64 + l];
    a_cur[1] = ap1[(size_t)(w * 2 + 1) * 64 + l];
    // relu(skip_sum + bias) -> s_m [t][m] stride 264 (rows 240..255 exact zeros)
    #pragma unroll
    for (int i2 = 0; i2 < 2; i2++) {
        int m_base = (w * 2 + i2) * 16 + quad * 4;
        float4 sb4 = make_float4(0.f, 0.f, 0.f, 0.f);
        bool valid = (m_base < 240);
        if (valid) sb4 = *(const float4*)(skbsum + m_base);
        #pragma unroll
        for (int n = 0; n < 4; n++) {
            float x0 = 0.f, x1 = 0.f, x2 = 0.f, x3 = 0.f;
            if (valid) {
                x0 = fmaxf(sacc[i2][n][0] + sb4.x, 0.f);
                x1 = fmaxf(sacc[i2][n][1] + sb4.y, 0.f);
                x2 = fmaxf(sacc[i2][n][2] + sb4.z, 0.f);
                x3 = fmaxf(sacc[i2][n][3] + sb4.w, 0.f);
            }
            int t = n * 16 + tloc;
            *(unsigned*)&s_m[t * 264 + m_base]     = pack2(x0, x1);
            *(unsigned*)&s_m[t * 264 + m_base + 2] = pack2(x2, x3);
        }
    }
    __syncthreads();
    // GEMM h1 (2 mt/wave)
    f32x4 acc[2][4];
    #pragma unroll
    for (int i = 0; i < 2; i++)
        #pragma unroll
        for (int n = 0; n < 4; n++) acc[i][n] = (f32x4){0.f, 0.f, 0.f, 0.f};
    for (int ks = 0; ks < 8; ks++) {
        if (ks < 7) {
            #pragma unroll
            for (int i = 0; i < 2; i++)
                a_nxt[i] = ap1[((size_t)(ks + 1) * 16 + w * 2 + i) * 64 + l];
        }
        short8 b[4];
        int k0 = ks * 32 + quad * 8;
        #pragma unroll
        for (int n = 0; n < 4; n++)
            b[n] = *(const short8*)&s_m[(n * 16 + tloc) * 264 + k0];
        #pragma unroll
        for (int i = 0; i < 2; i++)
            #pragma unroll
            for (int n = 0; n < 4; n++) acc[i][n] = MFMA(a_cur[i], b[n], acc[i][n]);
        #pragma unroll
        for (int i = 0; i < 2; i++) a_cur[i] = a_nxt[i];
    }
    unsigned ylo[2][4], yhi[2][4];
    #pragma unroll
    for (int i = 0; i < 2; i++) {
        int m_base = (w * 2 + i) * 16 + quad * 4;
        float4 b1 = *(const float4*)(h1_b + m_base);
        #pragma unroll
        for (int n = 0; n < 4; n++) {
            float y0 = fmaxf(acc[i][n][0] + b1.x, 0.f);
            float y1v = fmaxf(acc[i][n][1] + b1.y, 0.f);
            float y2 = fmaxf(acc[i][n][2] + b1.z, 0.f);
            float y3 = fmaxf(acc[i][n][3] + b1.w, 0.f);
            ylo[i][n] = pack2(y0, y1v);
            yhi[i][n] = pack2(y2, y3);
        }
    }
    const short8* ap2 = (const short8*)h2f;
    #pragma unroll
    for (int i = 0; i < 2; i++) a_cur[i] = ap2[(size_t)(w * 2 + i) * 64 + l];
    __syncthreads();
    #pragma unroll
    for (int i = 0; i < 2; i++) {
        int m_base = (w * 2 + i) * 16 + quad * 4;
        #pragma unroll
        for (int n = 0; n < 4; n++) {
            int t = n * 16 + tloc;
            *(unsigned*)&s_m[t * 264 + m_base]     = ylo[i][n];
            *(unsigned*)&s_m[t * 264 + m_base + 2] = yhi[i][n];
        }
    }
    __syncthreads();
    // GEMM h2
    #pragma unroll
    for (int i = 0; i < 2; i++)
        #pragma unroll
        for (int n = 0; n < 4; n++) acc[i][n] = (f32x4){0.f, 0.f, 0.f, 0.f};
    for (int ks = 0; ks < 8; ks++) {
        if (ks < 7) {
            #pragma unroll
            for (int i = 0; i < 2; i++)
                a_nxt[i] = ap2[((size_t)(ks + 1) * 16 + w * 2 + i) * 64 + l];
        }
        short8 b[4];
        int k0 = ks * 32 + quad * 8;
        #pragma unroll
        for (int n = 0; n < 4; n++)
            b[n] = *(const short8*)&s_m[(n * 16 + tloc) * 264 + k0];
        #pragma unroll
        for (int i = 0; i < 2; i++)
            #pragma unroll
            for (int n = 0; n < 4; n++) acc[i][n] = MFMA(a_cur[i], b[n], acc[i][n]);
        #pragma unroll
        for (int i = 0; i < 2; i++) a_cur[i] = a_nxt[i];
    }
    #pragma unroll
    for (int i = 0; i < 2; i++) {
        int m_base = (w * 2 + i) * 16 + quad * 4;
        float4 b2 = *(const float4*)(h2_b + m_base);
        float bb[4] = {b2.x, b2.y, b2.z, b2.w};
        #pragma unroll
        for (int n = 0; n < 4; n++) {
            int t = t0 + n * 16 + tloc;
            if (t >= L_LEN) continue;
            #pragma unroll
            for (int r = 0; r < 4; r++)
                out[(size_t)(m_base + r) * L_LEN + t] = acc[i][n][r] + bb[r];
        }
    }
}

extern "C" void kernel_launch(void* const* d_in, const int* in_sizes, int n_in,
                              void* d_out, int out_size, void* d_ws, size_t ws_size,
                              hipStream_t stream) {
    const float* wav   = (const float*)d_in[0];
    const float* mel   = (const float*)d_in[1];
    const float* up_w  = (const float*)d_in[2];
    const float* up_b  = (const float*)d_in[3];
    const float* in_w  = (const float*)d_in[4];
    const float* in_b  = (const float*)d_in[5];
    const float* bc_w  = (const float*)d_in[6];
    const float* bc_b  = (const float*)d_in[7];
    const float* bq_w  = (const float*)d_in[8];
    const float* bq_b  = (const float*)d_in[9];
    const float* bs_w  = (const float*)d_in[10];
    const float* bs_b  = (const float*)d_in[11];
    const float* br_w  = (const float*)d_in[12];
    const float* br_b  = (const float*)d_in[13];
    const float* h1_w  = (const float*)d_in[14];
    const float* h1_b  = (const float*)d_in[15];
    const float* h2_w  = (const float*)d_in[16];
    const float* h2_b  = (const float*)d_in[17];

    char* wsb = (char*)d_ws;
    const bool use_h = (ws_size >= NEED_H);

    if (use_h) {
        u16*   condT = (u16*)(wsb + H2_CONDT);
        u16*   bfA   = (u16*)(wsb + H2_BFA);
        u16*   bfB   = (u16*)(wsb + H2_BFB);
        u16*   zfrag = (u16*)(wsb + H2_ZFRAG);
        u16*   skf   = (u16*)(wsb + H2_SKF);
        u16*   rf    = (u16*)(wsb + H2_RF);
        u16*   h1f   = (u16*)(wsb + H2_H1F);
        u16*   h2f   = (u16*)(wsb + H2_H2F);
        float* zb    = (float*)(wsb + H2_ZB);
        float* skbs  = (float*)(wsb + H2_SKBS);
        u16*   hall  = (u16*)(wsb + H2_HALL);
        u16*   upf   = (u16*)(wsb + H2_HALL);   // dead after k_up; hall writes come later

        k_prep_zfrag <<<5120, 256, 0, stream>>>(bc_w, bq_w, zfrag);
        k_prep_skfrag<<<2048, 256, 0, stream>>>(bs_w, skf);
        k_prep_rfrag <<<1024, 256, 0, stream>>>(br_w, rf);
        k_prep_h1frag<<<256, 256, 0, stream>>>(h1_w, h1f);
        k_prep_h2frag<<<256, 256, 0, stream>>>(h2_w, h2f);
        k_prep_upfrag<<<25600, 256, 0, stream>>>(up_w, upf);
        k_prep_zbias <<<16, 256, 0, stream>>>(bc_b, bq_b, zb);
        k_prep_skbsum<<<1, 256, 0, stream>>>(bs_b, skbs);
        k_res_initTb <<<(L_LEN * RCH + 255) / 256, 256, 0, stream>>>(wav, in_w, in_b, bfA);
        k_up<<<dim3(256, 3), 256, 0, stream>>>(mel, upf, up_b, condT);

        u16* rin = bfA;
        u16* rout = bfB;
        // layers 0-3 fused (dils 1,2,4,8; halo 16)
        k_block_g4<<<NT, 512, 0, stream>>>(condT, rin, rout, hall, zfrag, rf, zb, br_b, 0);
        { u16* t = rin; rin = rout; rout = t; }
        // layers 4-7 single (dils 16,32,64,128)
        for (int i = 4; i < 8; i++) {
            k_block_h4<<<NT, 512, 0, stream>>>(condT, rin, rout,
                                               hall + (size_t)i * (size_t)L_LEN * 120,
                                               zfrag, rf, zb, br_b, i, 1 << (i & 7));
            u16* t = rin; rin = rout; rout = t;
        }
        // layers 8-11 fused
        k_block_g4<<<NT, 512, 0, stream>>>(condT, rin, rout, hall, zfrag, rf, zb, br_b, 8);
        { u16* t = rin; rin = rout; rout = t; }
        // layers 12-15 single
        for (int i = 12; i < 16; i++) {
            k_block_h4<<<NT, 512, 0, stream>>>(condT, rin, rout,
                                               hall + (size_t)i * (size_t)L_LEN * 120,
                                               zfrag, rf, zb, br_b, i, 1 << (i & 7));
            u16* t = rin; rin = rout; rout = t;
        }
        k_final_h3<<<NT, 512, 0, stream>>>(hall, skf, h1f, h2f, skbs, h1_b, h2_b,
                                           (float*)d_out);
    } else {
        // ---- proven fallback path, byte-identical behavior ----
        u16*   condT = (u16*)(wsb + O_CONDT);
        float* resA  = (float*)(wsb + O_RESA);
        float* resB  = (float*)(wsb + O_RESB);
        u16*   skipT = (u16*)(wsb + O_SKIP);
        u16*   zfrag = (u16*)(wsb + O_ZFRAG);
        u16*   skf   = (u16*)(wsb + O_SKF);
        u16*   rf    = (u16*)(wsb + O_RF);
        u16*   h1f   = (u16*)(wsb + O_H1F);
        u16*   h2f   = (u16*)(wsb + O_H2F);
        u16*   upf   = (u16*)(wsb + O_UPF);
        float* zb    = (float*)(wsb + O_ZB);
        float* skb   = (float*)(wsb + O_SKB);

        k_prep_zfrag <<<5120, 256, 0, stream>>>(bc_w, bq_w, zfrag);
        k_prep_skfrag<<<2048, 256, 0, stream>>>(bs_w, skf);
        k_prep_rfrag <<<1024, 256, 0, stream>>>(br_w, rf);
        k_prep_h1frag<<<256, 256, 0, stream>>>(h1_w, h1f);
        k_prep_h2frag<<<256, 256, 0, stream>>>(h2_w, h2f);
        k_prep_upfrag<<<25600, 256, 0, stream>>>(up_w, upf);
        k_prep_zbias <<<16, 256, 0, stream>>>(bc_b, bq_b, zb);
        k_prep_skbias<<<15, 256, 0, stream>>>(bs_b, skb);
        k_res_initT  <<<(L_LEN * RCH + 255) / 256, 256, 0, stream>>>(wav, in_w, in_b, resA);
        k_up<<<dim3(256, 3), 256, 0, stream>>>(mel, upf, up_b, condT);

        for (int i = 0; i < NBLK; i++) {
            int d = 1 << (i & 7);
            const float* rin = (i & 1) ? resB : resA;
            float* rout      = (i & 1) ? resA : resB;
            k_block<<<NT, 512, 0, stream>>>(condT, rin, rout, skipT, zfrag, skf, rf,
                                            zb, skb, br_b, i, d, (i == 0) ? 1 : 0);
        }
        k_final<<<NT, 512, 0, stream>>>(skipT, h1f, h2f, h1_b, h2_b, (float*)d_out);
    }
}